// Round 9
// baseline (505.439 us; speedup 1.0000x reference)
//
#include <hip/hip_runtime.h>
#include <stdint.h>

// Swin block: B=64, H=W=56, C=128, HID=512, WS=7, NH=4, SHIFT=3
static constexpr int Bz   = 64;
static constexpr int HH   = 56, WWp = 56;
static constexpr int C    = 128, HID = 512;
static constexpr int L    = HH * WWp;        // 3136
static constexpr int M    = Bz * L;          // 200704
static constexpr int NWIN = Bz * 64;         // 4096 windows
static constexpr int NH   = 4;
static constexpr int SHIFT = 3;

typedef __bf16 bf16x8 __attribute__((ext_vector_type(8)));
typedef float  f32x4  __attribute__((ext_vector_type(4)));

__device__ __forceinline__ float bf2f(unsigned short u) {
    return __uint_as_float(((unsigned int)u) << 16);
}
__device__ __forceinline__ unsigned short f2bf(float f) {
    unsigned int u = __float_as_uint(f);
    return (unsigned short)((u + 0x7FFFu + ((u >> 16) & 1u)) >> 16);
}
__device__ __forceinline__ unsigned lds_addr(const void* p) {
    return (unsigned)(size_t)(__attribute__((address_space(3))) const char*)p;
}
// tanh-form gelu, one v_exp; max |dev| from exact erf-gelu ~7e-4.
__device__ __forceinline__ float gelu_f(float x) {
    float y2 = 1.5957691216057308f * (x + 0.044715f * x * x * x);  // 2*sqrt(2/pi)*(...)
    float e  = __expf(y2);
    float t  = 1.0f - 2.0f / (e + 1.0f);
    return 0.5f * x * (1.0f + t);
}

// window-order row m -> original (b,l) row: roll(-SHIFT) + 7x7 partition.
__device__ __forceinline__ int win2orig(int m) {
    int w = m / 49, t = m - w * 49;
    int b = w >> 6, wi = (w >> 3) & 7, wj = w & 7;
    int ti = t / 7, tj = t - ti * 7;
    int i = wi * 7 + ti + SHIFT; if (i >= HH) i -= HH;
    int j = wj * 7 + tj + SHIFT; if (j >= WWp) j -= WWp;
    return b * L + i * WWp + j;
}

__device__ __forceinline__ void async_copy16(void* ldsdst, const void* gsrc) {
    __builtin_amdgcn_global_load_lds(
        (const __attribute__((address_space(1))) unsigned int*)gsrc,
        (__attribute__((address_space(3))) unsigned int*)ldsdst,
        16, 0, 0);
}

// Weights fp32->bf16 (196608 elems) + bias fragment table (16384 floats).
// biasd layout: [h][lane][mi][ni][r]; -1e30 for j>=49, 0 for i>=49.
__global__ __launch_bounds__(256) void wconv_kernel(
    const float* __restrict__ qkvw, const float* __restrict__ projw,
    const float* __restrict__ fc1w, const float* __restrict__ fc2w,
    const float* __restrict__ rpb, float* __restrict__ biasd,
    unsigned short* __restrict__ wb) {
    int i = blockIdx.x * 256 + threadIdx.x;
    float v;
    if (i < 49152)       v = qkvw[i];
    else if (i < 65536)  v = projw[i - 49152];
    else if (i < 131072) v = fc1w[i - 65536];
    else                 v = fc2w[i - 131072];
    wb[i] = f2bf(v);
    if (i < 16384) {
        int h = i >> 12, l = (i >> 6) & 63, f = i & 63;
        int mi = f >> 4, ni = (f >> 2) & 3, r = f & 3;
        int ii = mi * 16 + (l >> 4) * 4 + r;
        int jj = ni * 16 + (l & 15);
        float bv;
        if (jj >= 49)      bv = -1e30f;
        else if (ii >= 49) bv = 0.f;
        else {
            int yi = ii / 7, xi = ii - yi * 7, yj = jj / 7, xj = jj - yj * 7;
            bv = rpb[((yi - yj + 6) * 13 + (xi - xj + 6)) * NH + h];
        }
        biasd[i] = bv;
    }
}

// LayerNorm over C=128, fp32 in -> bf16 out. 1 wave/row, 4 rows/block.
__global__ __launch_bounds__(256) void ln_kernel(const float* __restrict__ in,
                                                 const float* __restrict__ g,
                                                 const float* __restrict__ bta,
                                                 unsigned short* __restrict__ out) {
    int row  = blockIdx.x * 4 + (threadIdx.x >> 6);
    int lane = threadIdx.x & 63;
    const float2 v = ((const float2*)(in + (long)row * C))[lane];
    float s  = v.x + v.y;
    float ss = v.x * v.x + v.y * v.y;
#pragma unroll
    for (int off = 32; off >= 1; off >>= 1) {
        s  += __shfl_xor(s, off);
        ss += __shfl_xor(ss, off);
    }
    float mu  = s * (1.0f / C);
    float var = ss * (1.0f / C) - mu * mu;
    float rs  = rsqrtf(var + 1e-5f);
    float2 gg = ((const float2*)g)[lane];
    float2 bb = ((const float2*)bta)[lane];
    ushort2 o;
    o.x = f2bf((v.x - mu) * rs * gg.x + bb.x);
    o.y = f2bf((v.y - mu) * rs * gg.y + bb.y);
    ((ushort2*)(out + (long)row * C))[lane] = o;
}

// Pipelined LDS-staged MFMA NT GEMM, operand-swapped (see round 6).
// MODE 0: qkv (gather rows; q scaled; k [wh][49][32]; v^T [wh][32][64])
// MODE 1: proj (+ resid fp32 x; fused LN2 -> x2b AND h2n, scattered rows)
template<int MODE, int K, int NB, bool GATHER>
__global__ __launch_bounds__(256) void gemm_pipe(
    const unsigned short* __restrict__ A,
    const unsigned short* __restrict__ Wb,
    const float* __restrict__ bias,
    const float* __restrict__ residf,
    const unsigned short* __restrict__ residb,
    const float* __restrict__ g2, const float* __restrict__ b2,
    float* __restrict__ outf,
    unsigned short* __restrict__ outb,
    unsigned short* __restrict__ outb2)
{
    constexpr int KH = K / 64;          // K-halves
    constexpr bool BIGK = (K > 128);
    __shared__ char lds[65536];
    char* ldsA = lds;                   // BIGK: dbuf 2x16KB ; else full 32KB
    char* ldsB = lds + 32768;           // dbuf 2x16KB
    const int tid = threadIdx.x;
    const int wid = tid >> 6, lane = tid & 63;
    const int g = lane >> 4, lr = lane & 15;
    const int wm = wid >> 1, wn = wid & 1;
    const int mbase = blockIdx.x * 128;

    auto stageAfull = [&]() {
#pragma unroll
        for (int i = 0; i < 8; ++i) {
            const int c = i * 4 + wid;
            const int r = (c << 2) + (lane >> 4);
            const int s = (lane & 15) ^ (r & 15);
            long arow = GATHER ? (long)win2orig(mbase + r) : (long)(mbase + r);
            async_copy16(ldsA + c * 1024, (const char*)A + arow * (K * 2) + s * 16);
        }
    };
    auto stageAhalf = [&](int buf, int kh) {
#pragma unroll
        for (int i = 0; i < 4; ++i) {
            const int c = i * 4 + wid;
            const int r = (c << 3) + (lane >> 3);
            const int s = (lane & 7) ^ (r & 7);
            async_copy16(ldsA + buf * 16384 + c * 1024,
                         (const char*)A + (long)(mbase + r) * (K * 2) + kh * 128 + s * 16);
        }
    };
    auto stageBhalf = [&](int buf, int nb, int kh) {
#pragma unroll
        for (int i = 0; i < 4; ++i) {
            const int c = i * 4 + wid;
            const int r = (c << 3) + (lane >> 3);
            const int s = (lane & 7) ^ (r & 7);
            async_copy16(ldsB + buf * 16384 + c * 1024,
                         (const char*)Wb + (long)(nb * 128 + r) * (K * 2) + kh * 128 + s * 16);
        }
    };

    if constexpr (!BIGK) stageAfull(); else stageAhalf(0, 0);
    stageBhalf(0, 0, 0);
    __syncthreads();
    int cur = 0;

    for (int nb = 0; nb < NB; ++nb) {
        const int nbase = nb * 128;
        f32x4 acc[4][4] = {};
        for (int kh = 0; kh < KH; ++kh) {
            const bool last = (nb == NB - 1) && (kh == KH - 1);
            if (!last) {
                const int nnb = (kh == KH - 1) ? nb + 1 : nb;
                const int nkh = (kh == KH - 1) ? 0 : kh + 1;
                if constexpr (BIGK) stageAhalf(cur ^ 1, nkh);
                stageBhalf(cur ^ 1, nnb, nkh);
            }
#pragma unroll
            for (int kkh = 0; kkh < 2; ++kkh) {
                bf16x8 af[4], bfr[4];
#pragma unroll
                for (int mi = 0; mi < 4; ++mi) {
                    const int ra = wm * 64 + mi * 16 + lr;
                    if constexpr (BIGK) {
                        af[mi] = *(const bf16x8*)(ldsA + cur * 16384 + ra * 128 + (((kkh * 4 + g) ^ (ra & 7)) * 16));
                    } else {
                        const int kk = kh * 2 + kkh;
                        af[mi] = *(const bf16x8*)(ldsA + ra * 256 + (((kk * 4 + g) ^ (ra & 15)) * 16));
                    }
                }
#pragma unroll
                for (int ni = 0; ni < 4; ++ni) {
                    const int rb = wn * 64 + ni * 16 + lr;
                    bfr[ni] = *(const bf16x8*)(ldsB + cur * 16384 + rb * 128 + (((kkh * 4 + g) ^ (rb & 7)) * 16));
                }
#pragma unroll
                for (int mi = 0; mi < 4; ++mi)
#pragma unroll
                    for (int ni = 0; ni < 4; ++ni)
                        acc[mi][ni] = __builtin_amdgcn_mfma_f32_16x16x32_bf16(bfr[ni], af[mi], acc[mi][ni], 0, 0, 0);
            }
            if (!last) { __syncthreads(); cur ^= 1; }
        }

        // ---- Epilogue for this nb (swapped layout) ----
        if constexpr (MODE == 0) {
            const int prt = nb;   // within-block n range is exactly 128
#pragma unroll
            for (int mi = 0; mi < 4; ++mi) {
                const int gm = mbase + wm * 64 + mi * 16 + lr;
                const int w = gm / 49, t = gm - w * 49;
#pragma unroll
                for (int ni = 0; ni < 4; ++ni) {
                    const int nloc = wn * 64 + ni * 16 + g * 4;
                    const int hh = nloc >> 5, dd = nloc & 31;
                    const f32x4 b4 = *(const f32x4*)&bias[nbase + nloc];
                    if (prt == 2) {
                        const long dbase = 2L * M * 128 + (((long)(w * 4 + hh)) * 32 + dd) * 64 + t;
#pragma unroll
                        for (int rg = 0; rg < 4; ++rg)
                            outb[dbase + rg * 64] = f2bf(acc[mi][ni][rg] + b4[rg]);
                    } else {
                        const float sc = (prt == 0) ? 0.17677669529663687f : 1.0f;
                        ushort4 pw;
                        pw.x = f2bf((acc[mi][ni][0] + b4[0]) * sc);
                        pw.y = f2bf((acc[mi][ni][1] + b4[1]) * sc);
                        pw.z = f2bf((acc[mi][ni][2] + b4[2]) * sc);
                        pw.w = f2bf((acc[mi][ni][3] + b4[3]) * sc);
                        *(ushort4*)(outb + (long)prt * M * 128 + (((long)(w * 4 + hh)) * 49 + t) * 32 + dd) = pw;
                    }
                }
            }
        } else {
            // MODE 1: x2 = x + (o@W + b); then LN2 in-register (NB==1).
            int rr[4];
#pragma unroll
            for (int mi = 0; mi < 4; ++mi)
                rr[mi] = win2orig(mbase + wm * 64 + mi * 16 + lr);
#pragma unroll
            for (int mi = 0; mi < 4; ++mi)
#pragma unroll
                for (int ni = 0; ni < 4; ++ni) {
                    const int nloc = wn * 64 + ni * 16 + g * 4;
                    const f32x4 b4 = *(const f32x4*)&bias[nloc];
                    const f32x4 r4 = *(const f32x4*)&residf[(long)rr[mi] * C + nloc];
                    acc[mi][ni] += b4 + r4;
                }
            float sA[4], qA[4];
#pragma unroll
            for (int mi = 0; mi < 4; ++mi) {
                float s = 0.f, q = 0.f;
#pragma unroll
                for (int ni = 0; ni < 4; ++ni)
#pragma unroll
                    for (int rg = 0; rg < 4; ++rg) {
                        float v = acc[mi][ni][rg];
                        s += v; q += v * v;
                    }
                s += __shfl_xor(s, 16); q += __shfl_xor(q, 16);
                s += __shfl_xor(s, 32); q += __shfl_xor(q, 32);
                sA[mi] = s; qA[mi] = q;
            }
            float* lp = (float*)lds;    // reuse: [wm][64][wn][2] = 512 floats
            __syncthreads();
            if (g == 0) {
#pragma unroll
                for (int mi = 0; mi < 4; ++mi) {
                    const int r64 = mi * 16 + lr;
                    lp[((wm * 64 + r64) * 2 + wn) * 2 + 0] = sA[mi];
                    lp[((wm * 64 + r64) * 2 + wn) * 2 + 1] = qA[mi];
                }
            }
            __syncthreads();
#pragma unroll
            for (int mi = 0; mi < 4; ++mi) {
                const int r64 = mi * 16 + lr;
                const float st = sA[mi] + lp[((wm * 64 + r64) * 2 + (wn ^ 1)) * 2 + 0];
                const float qt = qA[mi] + lp[((wm * 64 + r64) * 2 + (wn ^ 1)) * 2 + 1];
                const float mu = st * (1.0f / C);
                const float var = qt * (1.0f / C) - mu * mu;
                const float rs = rsqrtf(var + 1e-5f);
                const long rbase = (long)rr[mi] * C;
#pragma unroll
                for (int ni = 0; ni < 4; ++ni) {
                    const int nloc = wn * 64 + ni * 16 + g * 4;
                    ushort4 px, ph;
#pragma unroll
                    for (int rg = 0; rg < 4; ++rg) {
                        const float xv = acc[mi][ni][rg];
                        const float hv = (xv - mu) * rs * g2[nloc + rg] + b2[nloc + rg];
                        ((unsigned short*)&px)[rg] = f2bf(xv);
                        ((unsigned short*)&ph)[rg] = f2bf(hv);
                    }
                    *(ushort4*)(outb2 + rbase + nloc) = px;
                    *(ushort4*)(outb  + rbase + nloc) = ph;
                }
            }
        }
    }
}

// Fused MLP v3: out = x2 + fc2(gelu(fc1(h2n))). 64-row block, 4 waves (2x2):
// wave = 32 rows x 64 cols. NO weight staging: W1/W2 fragments loaded direct
// from global (both 128KB, L2-resident -> only latency, hidden by occupancy).
// P double-buffered in LDS (2x16KB) -> exactly ONE barrier per chunk:
//   chunk c: stage-1 (W1 from L2, A in regs) -> gelu -> write P[c&1]
//            __syncthreads -> stage-2 (read P[c&1], W2 from L2)
// Safety: a wave entering chunk c+1 stage-1 passed barrier(c), which requires
// all waves to have finished chunk c-1 stage-2 (program order) -> no overlap
// on P[(c+1)&1]. LDS 32KB -> 5 blocks/CU; ~130 VGPR -> 3 waves/SIMD.
__global__ __launch_bounds__(256) void mlp_fused(
    const unsigned short* __restrict__ A,     // h2n [M][128] bf16
    const unsigned short* __restrict__ W1,    // [512][128] bf16
    const unsigned short* __restrict__ W2,    // [128][512] bf16
    const float* __restrict__ b1,             // [512]
    const float* __restrict__ b2,             // [128]
    const unsigned short* __restrict__ resid, // x2b [M][128] bf16
    float* __restrict__ out)                  // [M][128] fp32
{
    __shared__ char ldsP[2][16384];
    const int tid = threadIdx.x;
    const int wid = tid >> 6, lane = tid & 63;
    const int g = lane >> 4, lr = lane & 15;
    const int wm = wid >> 1, wn = wid & 1;
    const int mbase = blockIdx.x * 64;

    // A-frags to registers: row = mbase+wm*32+mi*16+lr, k = kk*32+g*8
    bf16x8 af[2][4];
#pragma unroll
    for (int mi = 0; mi < 2; ++mi) {
        const long rb = (long)(mbase + wm * 32 + mi * 16 + lr) * 128;
#pragma unroll
        for (int kk = 0; kk < 4; ++kk)
            af[mi][kk] = *(const bf16x8*)(A + rb + kk * 32 + g * 8);
    }

    f32x4 oacc[2][4] = {};

    for (int c = 0; c < 4; ++c) {
        char* P = ldsP[c & 1];
        // ---- stage-1: p = A @ W1(c)^T, k = 128; W1 frags direct from L2 ----
        f32x4 pacc[2][4] = {};
        __builtin_amdgcn_s_setprio(1);
#pragma unroll
        for (int kk = 0; kk < 4; ++kk) {
            bf16x8 w1f[4];
#pragma unroll
            for (int ni = 0; ni < 4; ++ni)
                w1f[ni] = *(const bf16x8*)(W1 + (long)(c * 128 + wn * 64 + ni * 16 + lr) * 128 + kk * 32 + g * 8);
#pragma unroll
            for (int mi = 0; mi < 2; ++mi)
#pragma unroll
                for (int ni = 0; ni < 4; ++ni)
                    pacc[mi][ni] = __builtin_amdgcn_mfma_f32_16x16x32_bf16(w1f[ni], af[mi][kk], pacc[mi][ni], 0, 0, 0);
        }
        __builtin_amdgcn_s_setprio(0);
        // ---- gelu + bias -> bf16 -> P[m][hid] (256B rows, 16-slot XOR) ----
        // thread holds p[m = wm*32+mi*16+lr][hid = wn*64+ni*16+g*4+rg]
#pragma unroll
        for (int mi = 0; mi < 2; ++mi) {
            const int m = wm * 32 + mi * 16 + lr;
#pragma unroll
            for (int ni = 0; ni < 4; ++ni) {
                const int h0 = wn * 64 + ni * 16 + g * 4;    // chunk-local hid
                const f32x4 b4 = *(const f32x4*)&b1[c * 128 + h0];
                ushort4 pw;
                pw.x = f2bf(gelu_f(pacc[mi][ni][0] + b4[0]));
                pw.y = f2bf(gelu_f(pacc[mi][ni][1] + b4[1]));
                pw.z = f2bf(gelu_f(pacc[mi][ni][2] + b4[2]));
                pw.w = f2bf(gelu_f(pacc[mi][ni][3] + b4[3]));
                const int slot = h0 >> 3;                     // 16B unit index
                *(ushort4*)(P + m * 256 + ((slot ^ (m & 15)) * 16) + (g & 1) * 8) = pw;
            }
        }
        __syncthreads();   // P(c) visible to all waves
        // ---- stage-2: oacc += P @ W2(c)^T, k = 128; W2 frags from L2 ----
        __builtin_amdgcn_s_setprio(1);
#pragma unroll
        for (int kk = 0; kk < 4; ++kk) {
            bf16x8 pf[2], w2f[4];
#pragma unroll
            for (int mi = 0; mi < 2; ++mi) {
                const int ra = wm * 32 + mi * 16 + lr;
                pf[mi] = *(const bf16x8*)(P + ra * 256 + (((kk * 4 + g) ^ (ra & 15)) * 16));
            }
#pragma unroll
            for (int ni = 0; ni < 4; ++ni)
                w2f[ni] = *(const bf16x8*)(W2 + (long)(wn * 64 + ni * 16 + lr) * 512 + c * 128 + kk * 32 + g * 8);
#pragma unroll
            for (int mi = 0; mi < 2; ++mi)
#pragma unroll
                for (int ni = 0; ni < 4; ++ni)
                    oacc[mi][ni] = __builtin_amdgcn_mfma_f32_16x16x32_bf16(w2f[ni], pf[mi], oacc[mi][ni], 0, 0, 0);
        }
        __builtin_amdgcn_s_setprio(0);
        // no trailing barrier: next chunk writes the OTHER P buffer (safe).
    }

    // ---- epilogue: out = oacc + b2 + resid (fp32) ----
#pragma unroll
    for (int mi = 0; mi < 2; ++mi) {
        const long gm = mbase + wm * 32 + mi * 16 + lr;
#pragma unroll
        for (int ni = 0; ni < 4; ++ni) {
            const int n0 = wn * 64 + ni * 16 + g * 4;
            const f32x4 b4 = *(const f32x4*)&b2[n0];
            const ushort4 r4 = *(const ushort4*)(resid + gm * C + n0);
            f32x4 o4;
            o4[0] = oacc[mi][ni][0] + b4[0] + bf2f(r4.x);
            o4[1] = oacc[mi][ni][1] + b4[1] + bf2f(r4.y);
            o4[2] = oacc[mi][ni][2] + b4[2] + bf2f(r4.z);
            o4[3] = oacc[mi][ni][3] + b4[3] + bf2f(r4.w);
            *(f32x4*)(out + gm * C + n0) = o4;
        }
    }
}

// MFMA attention: 1 block/window, 1 wave/head (unchanged, proven round 3).
__global__ __launch_bounds__(256) void attn_mfma(
    const unsigned short* __restrict__ qb,   // [wh][49][32], pre-scaled
    const unsigned short* __restrict__ kb,   // [wh][49][32]
    const unsigned short* __restrict__ vtb,  // [wh][32][64] (V^T)
    const float* __restrict__ biasd,         // [h][lane][mi][ni][r]
    unsigned short* __restrict__ ob)         // [w*49+t][128]
{
    __shared__ __align__(16) char Pt[4][8192];
    const int tid  = threadIdx.x;
    const int h    = tid >> 6;
    const int lane = tid & 63;
    const int g    = lane >> 4, lr = lane & 15;
    const int w    = blockIdx.x;
    const long wh  = (long)(w * 4 + h);
    const unsigned short* qp = qb  + wh * (49 * 32);
    const unsigned short* kp = kb  + wh * (49 * 32);
    const unsigned short* vp = vtb + wh * (32 * 64);

    bf16x8 qf[4], kf[4];
#pragma unroll
    for (int mi = 0; mi < 4; ++mi) {
        qf[mi] = *(const bf16x8*)(qp + (mi * 16 + lr) * 32 + g * 8);
        kf[mi] = *(const bf16x8*)(kp + (mi * 16 + lr) * 32 + g * 8);
    }
    f32x4 acc[4][4] = {};
#pragma unroll
    for (int mi = 0; mi < 4; ++mi)
#pragma unroll
        for (int ni = 0; ni < 4; ++ni)
            acc[mi][ni] = __builtin_amdgcn_mfma_f32_16x16x32_bf16(qf[mi], kf[ni], acc[mi][ni], 0, 0, 0);

    const float* bp = biasd + (h * 64 + lane) * 64;
    char* ptw = &Pt[h][0];
#pragma unroll
    for (int mi = 0; mi < 4; ++mi) {
#pragma unroll
        for (int ni = 0; ni < 4; ++ni)
            acc[mi][ni] += *(const f32x4*)(bp + mi * 16 + ni * 4);
#pragma unroll
        for (int c = 0; c < 4; ++c)
            acc[mi][3][c] = (lr == 0) ? acc[mi][3][c] : -1e30f;
        f32x4 mx;
#pragma unroll
        for (int c = 0; c < 4; ++c)
            mx[c] = fmaxf(fmaxf(acc[mi][0][c], acc[mi][1][c]), fmaxf(acc[mi][2][c], acc[mi][3][c]));
#pragma unroll
        for (int off = 1; off <= 8; off <<= 1)
#pragma unroll
            for (int c = 0; c < 4; ++c)
                mx[c] = fmaxf(mx[c], __shfl_xor(mx[c], off));
        f32x4 sum = {};
#pragma unroll
        for (int ni = 0; ni < 4; ++ni)
#pragma unroll
            for (int c = 0; c < 4; ++c) {
                float e = __expf(acc[mi][ni][c] - mx[c]);
                acc[mi][ni][c] = e;
                sum[c] += e;
            }
#pragma unroll
        for (int off = 1; off <= 8; off <<= 1)
#pragma unroll
            for (int c = 0; c < 4; ++c)
                sum[c] += __shfl_xor(sum[c], off);
        f32x4 inv;
#pragma unroll
        for (int c = 0; c < 4; ++c)
            inv[c] = __builtin_amdgcn_rcpf(sum[c]);
#pragma unroll
        for (int ni = 0; ni < 4; ++ni) {
            ushort4 pw;
            pw.x = f2bf(acc[mi][ni][0] * inv[0]);
            pw.y = f2bf(acc[mi][ni][1] * inv[1]);
            pw.z = f2bf(acc[mi][ni][2] * inv[2]);
            pw.w = f2bf(acc[mi][ni][3] * inv[3]);
            int jb  = ni * 4 + (lr >> 2);
            int tix = (((jb >> 3) * 2 + (jb & 1)) * 4 + mi) * 4 + ((jb >> 1) & 3);
            *(ushort4*)(ptw + tix * 128 + (lr & 3) * 32 + g * 8) = pw;
        }
    }
    __syncthreads();

    bf16x8 vf[2][2];
#pragma unroll
    for (int md = 0; md < 2; ++md) {
#pragma unroll
        for (int kk = 0; kk < 2; ++kk)
            vf[md][kk] = *(const bf16x8*)(vp + (md * 16 + lr) * 64 + kk * 32 + g * 8);
#pragma unroll
        for (int e = 0; e < 8; ++e)
            if (g * 8 + e > 16) vf[md][1][e] = (__bf16)0.0f;
    }

    const unsigned pbase = lds_addr(&Pt[h][0]);
    f32x4 accO[2][4] = {};
#pragma unroll
    for (int kk = 0; kk < 2; ++kk) {
        long tt[4][2];
#pragma unroll
        for (int ni = 0; ni < 4; ++ni)
#pragma unroll
            for (int s = 0; s < 2; ++s) {
                unsigned a = pbase + ((((kk * 2 + s) * 4 + ni) * 4 + g) * 128) + lr * 2;
                asm volatile("ds_read_b64_tr_b16 %0, %1" : "=v"(tt[ni][s]) : "v"(a));
            }
        asm volatile("s_waitcnt lgkmcnt(0)" ::: "memory");
        __builtin_amdgcn_sched_barrier(0);
#pragma unroll
        for (int ni = 0; ni < 4; ++ni) {
            union { int4 i4; bf16x8 v; } u;
            u.i4 = make_int4((int)tt[ni][0], (int)(tt[ni][0] >> 32),
                             (int)tt[ni][1], (int)(tt[ni][1] >> 32));
#pragma unroll
            for (int md = 0; md < 2; ++md)
                accO[md][ni] = __builtin_amdgcn_mfma_f32_16x16x32_bf16(vf[md][kk], u.v, accO[md][ni], 0, 0, 0);
        }
    }
#pragma unroll
    for (int ni = 0; ni < 4; ++ni) {
        int i = ni * 16 + lr;
        if (i < 49) {
#pragma unroll
            for (int md = 0; md < 2; ++md) {
                ushort4 ov;
                ov.x = f2bf(accO[md][ni][0]);
                ov.y = f2bf(accO[md][ni][1]);
                ov.z = f2bf(accO[md][ni][2]);
                ov.w = f2bf(accO[md][ni][3]);
                *(ushort4*)(ob + ((long)(w * 49 + i)) * 128 + h * 32 + md * 16 + g * 4) = ov;
            }
        }
    }
}

extern "C" void kernel_launch(void* const* d_in, const int* in_sizes, int n_in,
                              void* d_out, int out_size, void* d_ws, size_t ws_size,
                              hipStream_t stream) {
    const float* x      = (const float*)d_in[0];
    const float* n1g    = (const float*)d_in[1];
    const float* n1b    = (const float*)d_in[2];
    const float* qkv_w  = (const float*)d_in[3];
    const float* qkv_b  = (const float*)d_in[4];
    const float* proj_w = (const float*)d_in[5];
    const float* proj_b = (const float*)d_in[6];
    const float* rpb    = (const float*)d_in[7];
    const float* n2g    = (const float*)d_in[8];
    const float* n2b    = (const float*)d_in[9];
    const float* fc1_w  = (const float*)d_in[10];
    const float* fc1_b  = (const float*)d_in[11];
    const float* fc2_w  = (const float*)d_in[12];
    const float* fc2_b  = (const float*)d_in[13];
    float* out = (float*)d_out;

    // Workspace (~324 MB):
    //  [0,SZ)             hnorm -> o
    //  [SZ,3SZ+VT)        q | k | v^T
    //  [3SZ+VT, 4SZ+VT)   x2b bf16
    //  [4SZ+VT, 5SZ+VT)   h2n
    //  [5SZ+VT, ..)       weights bf16 (384KB) + biasd (64KB)
    char* ws = (char*)d_ws;
    const size_t SZ = (size_t)M * C * 2;                    // 51,380,224
    const size_t VT = (size_t)NWIN * NH * 32 * 64 * 2;      // 67,108,864
    unsigned short* hnorm  = (unsigned short*)(ws);
    unsigned short* qkvbuf = (unsigned short*)(ws + SZ);
    unsigned short* o      = hnorm;
    unsigned short* x2b    = (unsigned short*)(ws + 3 * SZ + VT);
    unsigned short* h2n    = (unsigned short*)(ws + 4 * SZ + VT);
    unsigned short* wb     = (unsigned short*)(ws + 5 * SZ + VT);
    float* biasd           = (float*)(ws + 5 * SZ + VT + 393216);
    unsigned short* wqkv = wb, *wproj = wb + 49152, *wfc1 = wb + 65536, *wfc2 = wb + 131072;

    wconv_kernel<<<768, 256, 0, stream>>>(qkv_w, proj_w, fc1_w, fc2_w, rpb, biasd, wb);
    ln_kernel<<<M / 4, 256, 0, stream>>>(x, n1g, n1b, hnorm);
    gemm_pipe<0, 128, 3, true ><<<M / 128, 256, 0, stream>>>(hnorm, wqkv, qkv_b, nullptr, nullptr, nullptr, nullptr, nullptr, qkvbuf, nullptr);
    attn_mfma<<<NWIN, 256, 0, stream>>>(qkvbuf, qkvbuf + (size_t)M * 128, qkvbuf + 2 * (size_t)M * 128, biasd, o);
    gemm_pipe<1, 128, 1, false><<<M / 128, 256, 0, stream>>>(o, wproj, proj_b, x, nullptr, n2g, n2b, nullptr, h2n, x2b);
    mlp_fused<<<M / 64, 256, 0, stream>>>(h2n, wfc1, wfc2, fc1_b, fc2_b, x2b, out);
}

// Round 10
// 435.814 us; speedup vs baseline: 1.1598x; 1.1598x over previous
//
#include <hip/hip_runtime.h>
#include <stdint.h>

// Swin block: B=64, H=W=56, C=128, HID=512, WS=7, NH=4, SHIFT=3
static constexpr int Bz   = 64;
static constexpr int HH   = 56, WWp = 56;
static constexpr int C    = 128, HID = 512;
static constexpr int L    = HH * WWp;        // 3136
static constexpr int M    = Bz * L;          // 200704
static constexpr int NWIN = Bz * 64;         // 4096 windows
static constexpr int NH   = 4;
static constexpr int SHIFT = 3;

typedef __bf16 bf16x8 __attribute__((ext_vector_type(8)));
typedef float  f32x4  __attribute__((ext_vector_type(4)));

__device__ __forceinline__ float bf2f(unsigned short u) {
    return __uint_as_float(((unsigned int)u) << 16);
}
__device__ __forceinline__ unsigned short f2bf(float f) {
    unsigned int u = __float_as_uint(f);
    return (unsigned short)((u + 0x7FFFu + ((u >> 16) & 1u)) >> 16);
}
__device__ __forceinline__ unsigned lds_addr(const void* p) {
    return (unsigned)(size_t)(__attribute__((address_space(3))) const char*)p;
}
// tanh-form gelu, one v_exp; max |dev| from exact erf-gelu ~7e-4.
__device__ __forceinline__ float gelu_f(float x) {
    float y2 = 1.5957691216057308f * (x + 0.044715f * x * x * x);  // 2*sqrt(2/pi)*(...)
    float e  = __expf(y2);
    float t  = 1.0f - 2.0f / (e + 1.0f);
    return 0.5f * x * (1.0f + t);
}

// window-order row m -> original (b,l) row: roll(-SHIFT) + 7x7 partition.
__device__ __forceinline__ int win2orig(int m) {
    int w = m / 49, t = m - w * 49;
    int b = w >> 6, wi = (w >> 3) & 7, wj = w & 7;
    int ti = t / 7, tj = t - ti * 7;
    int i = wi * 7 + ti + SHIFT; if (i >= HH) i -= HH;
    int j = wj * 7 + tj + SHIFT; if (j >= WWp) j -= WWp;
    return b * L + i * WWp + j;
}

__device__ __forceinline__ void async_copy16(void* ldsdst, const void* gsrc) {
    __builtin_amdgcn_global_load_lds(
        (const __attribute__((address_space(1))) unsigned int*)gsrc,
        (__attribute__((address_space(3))) unsigned int*)ldsdst,
        16, 0, 0);
}

// Weights fp32->bf16 (196608 elems) + bias fragment table (16384 floats).
// biasd layout: [h][lane][mi][ni][r]; -1e30 for j>=49, 0 for i>=49.
__global__ __launch_bounds__(256) void wconv_kernel(
    const float* __restrict__ qkvw, const float* __restrict__ projw,
    const float* __restrict__ fc1w, const float* __restrict__ fc2w,
    const float* __restrict__ rpb, float* __restrict__ biasd,
    unsigned short* __restrict__ wb) {
    int i = blockIdx.x * 256 + threadIdx.x;
    float v;
    if (i < 49152)       v = qkvw[i];
    else if (i < 65536)  v = projw[i - 49152];
    else if (i < 131072) v = fc1w[i - 65536];
    else                 v = fc2w[i - 131072];
    wb[i] = f2bf(v);
    if (i < 16384) {
        int h = i >> 12, l = (i >> 6) & 63, f = i & 63;
        int mi = f >> 4, ni = (f >> 2) & 3, r = f & 3;
        int ii = mi * 16 + (l >> 4) * 4 + r;
        int jj = ni * 16 + (l & 15);
        float bv;
        if (jj >= 49)      bv = -1e30f;
        else if (ii >= 49) bv = 0.f;
        else {
            int yi = ii / 7, xi = ii - yi * 7, yj = jj / 7, xj = jj - yj * 7;
            bv = rpb[((yi - yj + 6) * 13 + (xi - xj + 6)) * NH + h];
        }
        biasd[i] = bv;
    }
}

// LayerNorm over C=128, fp32 in -> bf16 out. 1 wave/row, 4 rows/block.
__global__ __launch_bounds__(256) void ln_kernel(const float* __restrict__ in,
                                                 const float* __restrict__ g,
                                                 const float* __restrict__ bta,
                                                 unsigned short* __restrict__ out) {
    int row  = blockIdx.x * 4 + (threadIdx.x >> 6);
    int lane = threadIdx.x & 63;
    const float2 v = ((const float2*)(in + (long)row * C))[lane];
    float s  = v.x + v.y;
    float ss = v.x * v.x + v.y * v.y;
#pragma unroll
    for (int off = 32; off >= 1; off >>= 1) {
        s  += __shfl_xor(s, off);
        ss += __shfl_xor(ss, off);
    }
    float mu  = s * (1.0f / C);
    float var = ss * (1.0f / C) - mu * mu;
    float rs  = rsqrtf(var + 1e-5f);
    float2 gg = ((const float2*)g)[lane];
    float2 bb = ((const float2*)bta)[lane];
    ushort2 o;
    o.x = f2bf((v.x - mu) * rs * gg.x + bb.x);
    o.y = f2bf((v.y - mu) * rs * gg.y + bb.y);
    ((ushort2*)(out + (long)row * C))[lane] = o;
}

// Pipelined LDS-staged MFMA NT GEMM, operand-swapped (see round 6).
// MODE 0: qkv (gather rows; q scaled; k [wh][49][32]; v^T [wh][32][64])
// MODE 1: proj (+ resid fp32 x; fused LN2 -> x2b AND h2n, scattered rows)
template<int MODE, int K, int NB, bool GATHER>
__global__ __launch_bounds__(256) void gemm_pipe(
    const unsigned short* __restrict__ A,
    const unsigned short* __restrict__ Wb,
    const float* __restrict__ bias,
    const float* __restrict__ residf,
    const unsigned short* __restrict__ residb,
    const float* __restrict__ g2, const float* __restrict__ b2,
    float* __restrict__ outf,
    unsigned short* __restrict__ outb,
    unsigned short* __restrict__ outb2)
{
    constexpr int KH = K / 64;          // K-halves
    constexpr bool BIGK = (K > 128);
    __shared__ char lds[65536];
    char* ldsA = lds;                   // BIGK: dbuf 2x16KB ; else full 32KB
    char* ldsB = lds + 32768;           // dbuf 2x16KB
    const int tid = threadIdx.x;
    const int wid = tid >> 6, lane = tid & 63;
    const int g = lane >> 4, lr = lane & 15;
    const int wm = wid >> 1, wn = wid & 1;
    const int mbase = blockIdx.x * 128;

    auto stageAfull = [&]() {
#pragma unroll
        for (int i = 0; i < 8; ++i) {
            const int c = i * 4 + wid;
            const int r = (c << 2) + (lane >> 4);
            const int s = (lane & 15) ^ (r & 15);
            long arow = GATHER ? (long)win2orig(mbase + r) : (long)(mbase + r);
            async_copy16(ldsA + c * 1024, (const char*)A + arow * (K * 2) + s * 16);
        }
    };
    auto stageAhalf = [&](int buf, int kh) {
#pragma unroll
        for (int i = 0; i < 4; ++i) {
            const int c = i * 4 + wid;
            const int r = (c << 3) + (lane >> 3);
            const int s = (lane & 7) ^ (r & 7);
            async_copy16(ldsA + buf * 16384 + c * 1024,
                         (const char*)A + (long)(mbase + r) * (K * 2) + kh * 128 + s * 16);
        }
    };
    auto stageBhalf = [&](int buf, int nb, int kh) {
#pragma unroll
        for (int i = 0; i < 4; ++i) {
            const int c = i * 4 + wid;
            const int r = (c << 3) + (lane >> 3);
            const int s = (lane & 7) ^ (r & 7);
            async_copy16(ldsB + buf * 16384 + c * 1024,
                         (const char*)Wb + (long)(nb * 128 + r) * (K * 2) + kh * 128 + s * 16);
        }
    };

    if constexpr (!BIGK) stageAfull(); else stageAhalf(0, 0);
    stageBhalf(0, 0, 0);
    __syncthreads();
    int cur = 0;

    for (int nb = 0; nb < NB; ++nb) {
        const int nbase = nb * 128;
        f32x4 acc[4][4] = {};
        for (int kh = 0; kh < KH; ++kh) {
            const bool last = (nb == NB - 1) && (kh == KH - 1);
            if (!last) {
                const int nnb = (kh == KH - 1) ? nb + 1 : nb;
                const int nkh = (kh == KH - 1) ? 0 : kh + 1;
                if constexpr (BIGK) stageAhalf(cur ^ 1, nkh);
                stageBhalf(cur ^ 1, nnb, nkh);
            }
#pragma unroll
            for (int kkh = 0; kkh < 2; ++kkh) {
                bf16x8 af[4], bfr[4];
#pragma unroll
                for (int mi = 0; mi < 4; ++mi) {
                    const int ra = wm * 64 + mi * 16 + lr;
                    if constexpr (BIGK) {
                        af[mi] = *(const bf16x8*)(ldsA + cur * 16384 + ra * 128 + (((kkh * 4 + g) ^ (ra & 7)) * 16));
                    } else {
                        const int kk = kh * 2 + kkh;
                        af[mi] = *(const bf16x8*)(ldsA + ra * 256 + (((kk * 4 + g) ^ (ra & 15)) * 16));
                    }
                }
#pragma unroll
                for (int ni = 0; ni < 4; ++ni) {
                    const int rb = wn * 64 + ni * 16 + lr;
                    bfr[ni] = *(const bf16x8*)(ldsB + cur * 16384 + rb * 128 + (((kkh * 4 + g) ^ (rb & 7)) * 16));
                }
#pragma unroll
                for (int mi = 0; mi < 4; ++mi)
#pragma unroll
                    for (int ni = 0; ni < 4; ++ni)
                        acc[mi][ni] = __builtin_amdgcn_mfma_f32_16x16x32_bf16(bfr[ni], af[mi], acc[mi][ni], 0, 0, 0);
            }
            if (!last) { __syncthreads(); cur ^= 1; }
        }

        // ---- Epilogue for this nb (swapped layout) ----
        if constexpr (MODE == 0) {
            const int prt = nb;   // within-block n range is exactly 128
#pragma unroll
            for (int mi = 0; mi < 4; ++mi) {
                const int gm = mbase + wm * 64 + mi * 16 + lr;
                const int w = gm / 49, t = gm - w * 49;
#pragma unroll
                for (int ni = 0; ni < 4; ++ni) {
                    const int nloc = wn * 64 + ni * 16 + g * 4;
                    const int hh = nloc >> 5, dd = nloc & 31;
                    const f32x4 b4 = *(const f32x4*)&bias[nbase + nloc];
                    if (prt == 2) {
                        const long dbase = 2L * M * 128 + (((long)(w * 4 + hh)) * 32 + dd) * 64 + t;
#pragma unroll
                        for (int rg = 0; rg < 4; ++rg)
                            outb[dbase + rg * 64] = f2bf(acc[mi][ni][rg] + b4[rg]);
                    } else {
                        const float sc = (prt == 0) ? 0.17677669529663687f : 1.0f;
                        ushort4 pw;
                        pw.x = f2bf((acc[mi][ni][0] + b4[0]) * sc);
                        pw.y = f2bf((acc[mi][ni][1] + b4[1]) * sc);
                        pw.z = f2bf((acc[mi][ni][2] + b4[2]) * sc);
                        pw.w = f2bf((acc[mi][ni][3] + b4[3]) * sc);
                        *(ushort4*)(outb + (long)prt * M * 128 + (((long)(w * 4 + hh)) * 49 + t) * 32 + dd) = pw;
                    }
                }
            }
        } else {
            // MODE 1: x2 = x + (o@W + b); then LN2 in-register (NB==1).
            int rr[4];
#pragma unroll
            for (int mi = 0; mi < 4; ++mi)
                rr[mi] = win2orig(mbase + wm * 64 + mi * 16 + lr);
#pragma unroll
            for (int mi = 0; mi < 4; ++mi)
#pragma unroll
                for (int ni = 0; ni < 4; ++ni) {
                    const int nloc = wn * 64 + ni * 16 + g * 4;
                    const f32x4 b4 = *(const f32x4*)&bias[nloc];
                    const f32x4 r4 = *(const f32x4*)&residf[(long)rr[mi] * C + nloc];
                    acc[mi][ni] += b4 + r4;
                }
            float sA[4], qA[4];
#pragma unroll
            for (int mi = 0; mi < 4; ++mi) {
                float s = 0.f, q = 0.f;
#pragma unroll
                for (int ni = 0; ni < 4; ++ni)
#pragma unroll
                    for (int rg = 0; rg < 4; ++rg) {
                        float v = acc[mi][ni][rg];
                        s += v; q += v * v;
                    }
                s += __shfl_xor(s, 16); q += __shfl_xor(q, 16);
                s += __shfl_xor(s, 32); q += __shfl_xor(q, 32);
                sA[mi] = s; qA[mi] = q;
            }
            float* lp = (float*)lds;    // reuse: [wm][64][wn][2] = 512 floats
            __syncthreads();
            if (g == 0) {
#pragma unroll
                for (int mi = 0; mi < 4; ++mi) {
                    const int r64 = mi * 16 + lr;
                    lp[((wm * 64 + r64) * 2 + wn) * 2 + 0] = sA[mi];
                    lp[((wm * 64 + r64) * 2 + wn) * 2 + 1] = qA[mi];
                }
            }
            __syncthreads();
#pragma unroll
            for (int mi = 0; mi < 4; ++mi) {
                const int r64 = mi * 16 + lr;
                const float st = sA[mi] + lp[((wm * 64 + r64) * 2 + (wn ^ 1)) * 2 + 0];
                const float qt = qA[mi] + lp[((wm * 64 + r64) * 2 + (wn ^ 1)) * 2 + 1];
                const float mu = st * (1.0f / C);
                const float var = qt * (1.0f / C) - mu * mu;
                const float rs = rsqrtf(var + 1e-5f);
                const long rbase = (long)rr[mi] * C;
#pragma unroll
                for (int ni = 0; ni < 4; ++ni) {
                    const int nloc = wn * 64 + ni * 16 + g * 4;
                    ushort4 px, ph;
#pragma unroll
                    for (int rg = 0; rg < 4; ++rg) {
                        const float xv = acc[mi][ni][rg];
                        const float hv = (xv - mu) * rs * g2[nloc + rg] + b2[nloc + rg];
                        ((unsigned short*)&px)[rg] = f2bf(xv);
                        ((unsigned short*)&ph)[rg] = f2bf(hv);
                    }
                    *(ushort4*)(outb2 + rbase + nloc) = px;
                    *(ushort4*)(outb  + rbase + nloc) = ph;
                }
            }
        }
    }
}

// Fused MLP v4 (= v2 schedule + register repair): out = x2+fc2(gelu(fc1(h2n))).
// 64-row block, 4 waves. W1 chunk LDS-staged (32KB, proven v2 schedule);
// P single 16KB buffer; W2 frags direct from L2. Stage-1 computes the
// 128-hid chunk in TWO 64-col passes (wave 2x2 over rows x 32-col slices)
// so pacc is 16 regs not 32; __launch_bounds__(256,3) pins allocation to
// <=170 regs -> 3 waves/SIMD (v2/v3 were 2 waves/SIMD = the 21% occupancy).
__global__ __launch_bounds__(256, 3) void mlp_fused(
    const unsigned short* __restrict__ A,     // h2n [M][128] bf16
    const unsigned short* __restrict__ W1,    // [512][128] bf16
    const unsigned short* __restrict__ W2,    // [128][512] bf16
    const float* __restrict__ b1,             // [512]
    const float* __restrict__ b2,             // [128]
    const unsigned short* __restrict__ resid, // x2b [M][128] bf16
    float* __restrict__ out)                  // [M][128] fp32
{
    __shared__ char ldsW[32768];
    __shared__ char ldsP[16384];
    const int tid = threadIdx.x;
    const int wid = tid >> 6, lane = tid & 63;
    const int g = lane >> 4, lr = lane & 15;
    const int wm = wid >> 1, wn = wid & 1;
    const int mbase = blockIdx.x * 64;

    // A-frags to registers: row = mbase+wm*32+mi*16+lr, k = kk*32+g*8
    bf16x8 af[2][4];
#pragma unroll
    for (int mi = 0; mi < 2; ++mi) {
        const long rb = (long)(mbase + wm * 32 + mi * 16 + lr) * 128;
#pragma unroll
        for (int kk = 0; kk < 4; ++kk)
            af[mi][kk] = *(const bf16x8*)(A + rb + kk * 32 + g * 8);
    }

    // stage W1 chunk c: 128 rows x 256B, 16-slot XOR swizzle (proven pattern)
    auto stageW1 = [&](int c) {
#pragma unroll
        for (int i = 0; i < 8; ++i) {
            const int cb = i * 4 + wid;          // 1KB unit = 4 rows
            const int r  = cb * 4 + g;
            const int s  = lr ^ (r & 15);
            async_copy16(ldsW + cb * 1024, (const char*)W1 + (long)(c * 128 + r) * 256 + s * 16);
        }
    };

    stageW1(0);
    f32x4 oacc[2][4] = {};

    for (int c = 0; c < 4; ++c) {
        __syncthreads();   // W1(c) staged (barrier drains vmcnt); P free
        // ---- stage-1: p = A @ W1(c)^T in two 64-col passes (pacc 16 regs) ----
#pragma unroll
        for (int hh = 0; hh < 2; ++hh) {
            f32x4 pacc[2][2] = {};
#pragma unroll
            for (int kk = 0; kk < 4; ++kk) {
                bf16x8 w1f[2];
#pragma unroll
                for (int ni = 0; ni < 2; ++ni) {
                    const int rb = hh * 64 + wn * 32 + ni * 16 + lr;
                    w1f[ni] = *(const bf16x8*)(ldsW + rb * 256 + (((kk * 4 + g) ^ (rb & 15)) * 16));
                }
#pragma unroll
                for (int mi = 0; mi < 2; ++mi)
#pragma unroll
                    for (int ni = 0; ni < 2; ++ni)
                        pacc[mi][ni] = __builtin_amdgcn_mfma_f32_16x16x32_bf16(w1f[ni], af[mi][kk], pacc[mi][ni], 0, 0, 0);
            }
            // gelu + bias -> bf16 -> ldsP[m][hid] (256B rows, 16-slot XOR)
            // thread holds p[m = wm*32+mi*16+lr][hid = hh*64+wn*32+ni*16+g*4+rg]
#pragma unroll
            for (int mi = 0; mi < 2; ++mi) {
                const int m = wm * 32 + mi * 16 + lr;
#pragma unroll
                for (int ni = 0; ni < 2; ++ni) {
                    const int h0 = hh * 64 + wn * 32 + ni * 16 + g * 4;  // chunk-local
                    const f32x4 b4 = *(const f32x4*)&b1[c * 128 + h0];
                    ushort4 pw;
                    pw.x = f2bf(gelu_f(pacc[mi][ni][0] + b4[0]));
                    pw.y = f2bf(gelu_f(pacc[mi][ni][1] + b4[1]));
                    pw.z = f2bf(gelu_f(pacc[mi][ni][2] + b4[2]));
                    pw.w = f2bf(gelu_f(pacc[mi][ni][3] + b4[3]));
                    *(ushort4*)(ldsP + m * 256 + (((h0 >> 3) ^ (m & 15)) * 16) + (g & 1) * 8) = pw;
                }
            }
        }
        __syncthreads();   // P(c) complete; W1 buffer free
        if (c < 3) stageW1(c + 1);   // overlaps with stage-2 below
        // ---- stage-2: oacc += P @ W2(c)^T, k = 128; W2 frags from L2 ----
#pragma unroll
        for (int kk = 0; kk < 4; ++kk) {
            bf16x8 pf[2], w2f[4];
#pragma unroll
            for (int mi = 0; mi < 2; ++mi) {
                const int ra = wm * 32 + mi * 16 + lr;
                pf[mi] = *(const bf16x8*)(ldsP + ra * 256 + (((kk * 4 + g) ^ (ra & 15)) * 16));
            }
#pragma unroll
            for (int ni = 0; ni < 4; ++ni)
                w2f[ni] = *(const bf16x8*)(W2 + (long)(wn * 64 + ni * 16 + lr) * 512 + c * 128 + kk * 32 + g * 8);
#pragma unroll
            for (int mi = 0; mi < 2; ++mi)
#pragma unroll
                for (int ni = 0; ni < 4; ++ni)
                    oacc[mi][ni] = __builtin_amdgcn_mfma_f32_16x16x32_bf16(w2f[ni], pf[mi], oacc[mi][ni], 0, 0, 0);
        }
    }

    // ---- epilogue: out = oacc + b2 + resid (fp32) ----
#pragma unroll
    for (int mi = 0; mi < 2; ++mi) {
        const long gm = mbase + wm * 32 + mi * 16 + lr;
#pragma unroll
        for (int ni = 0; ni < 4; ++ni) {
            const int n0 = wn * 64 + ni * 16 + g * 4;
            const f32x4 b4 = *(const f32x4*)&b2[n0];
            const ushort4 r4 = *(const ushort4*)(resid + gm * C + n0);
            f32x4 o4;
            o4[0] = oacc[mi][ni][0] + b4[0] + bf2f(r4.x);
            o4[1] = oacc[mi][ni][1] + b4[1] + bf2f(r4.y);
            o4[2] = oacc[mi][ni][2] + b4[2] + bf2f(r4.z);
            o4[3] = oacc[mi][ni][3] + b4[3] + bf2f(r4.w);
            *(f32x4*)(out + gm * C + n0) = o4;
        }
    }
}

// MFMA attention: 1 block/window, 1 wave/head (unchanged, proven round 3).
__global__ __launch_bounds__(256) void attn_mfma(
    const unsigned short* __restrict__ qb,   // [wh][49][32], pre-scaled
    const unsigned short* __restrict__ kb,   // [wh][49][32]
    const unsigned short* __restrict__ vtb,  // [wh][32][64] (V^T)
    const float* __restrict__ biasd,         // [h][lane][mi][ni][r]
    unsigned short* __restrict__ ob)         // [w*49+t][128]
{
    __shared__ __align__(16) char Pt[4][8192];
    const int tid  = threadIdx.x;
    const int h    = tid >> 6;
    const int lane = tid & 63;
    const int g    = lane >> 4, lr = lane & 15;
    const int w    = blockIdx.x;
    const long wh  = (long)(w * 4 + h);
    const unsigned short* qp = qb  + wh * (49 * 32);
    const unsigned short* kp = kb  + wh * (49 * 32);
    const unsigned short* vp = vtb + wh * (32 * 64);

    bf16x8 qf[4], kf[4];
#pragma unroll
    for (int mi = 0; mi < 4; ++mi) {
        qf[mi] = *(const bf16x8*)(qp + (mi * 16 + lr) * 32 + g * 8);
        kf[mi] = *(const bf16x8*)(kp + (mi * 16 + lr) * 32 + g * 8);
    }
    f32x4 acc[4][4] = {};
#pragma unroll
    for (int mi = 0; mi < 4; ++mi)
#pragma unroll
        for (int ni = 0; ni < 4; ++ni)
            acc[mi][ni] = __builtin_amdgcn_mfma_f32_16x16x32_bf16(qf[mi], kf[ni], acc[mi][ni], 0, 0, 0);

    const float* bp = biasd + (h * 64 + lane) * 64;
    char* ptw = &Pt[h][0];
#pragma unroll
    for (int mi = 0; mi < 4; ++mi) {
#pragma unroll
        for (int ni = 0; ni < 4; ++ni)
            acc[mi][ni] += *(const f32x4*)(bp + mi * 16 + ni * 4);
#pragma unroll
        for (int c = 0; c < 4; ++c)
            acc[mi][3][c] = (lr == 0) ? acc[mi][3][c] : -1e30f;
        f32x4 mx;
#pragma unroll
        for (int c = 0; c < 4; ++c)
            mx[c] = fmaxf(fmaxf(acc[mi][0][c], acc[mi][1][c]), fmaxf(acc[mi][2][c], acc[mi][3][c]));
#pragma unroll
        for (int off = 1; off <= 8; off <<= 1)
#pragma unroll
            for (int c = 0; c < 4; ++c)
                mx[c] = fmaxf(mx[c], __shfl_xor(mx[c], off));
        f32x4 sum = {};
#pragma unroll
        for (int ni = 0; ni < 4; ++ni)
#pragma unroll
            for (int c = 0; c < 4; ++c) {
                float e = __expf(acc[mi][ni][c] - mx[c]);
                acc[mi][ni][c] = e;
                sum[c] += e;
            }
#pragma unroll
        for (int off = 1; off <= 8; off <<= 1)
#pragma unroll
            for (int c = 0; c < 4; ++c)
                sum[c] += __shfl_xor(sum[c], off);
        f32x4 inv;
#pragma unroll
        for (int c = 0; c < 4; ++c)
            inv[c] = __builtin_amdgcn_rcpf(sum[c]);
#pragma unroll
        for (int ni = 0; ni < 4; ++ni) {
            ushort4 pw;
            pw.x = f2bf(acc[mi][ni][0] * inv[0]);
            pw.y = f2bf(acc[mi][ni][1] * inv[1]);
            pw.z = f2bf(acc[mi][ni][2] * inv[2]);
            pw.w = f2bf(acc[mi][ni][3] * inv[3]);
            int jb  = ni * 4 + (lr >> 2);
            int tix = (((jb >> 3) * 2 + (jb & 1)) * 4 + mi) * 4 + ((jb >> 1) & 3);
            *(ushort4*)(ptw + tix * 128 + (lr & 3) * 32 + g * 8) = pw;
        }
    }
    __syncthreads();

    bf16x8 vf[2][2];
#pragma unroll
    for (int md = 0; md < 2; ++md) {
#pragma unroll
        for (int kk = 0; kk < 2; ++kk)
            vf[md][kk] = *(const bf16x8*)(vp + (md * 16 + lr) * 64 + kk * 32 + g * 8);
#pragma unroll
        for (int e = 0; e < 8; ++e)
            if (g * 8 + e > 16) vf[md][1][e] = (__bf16)0.0f;
    }

    const unsigned pbase = lds_addr(&Pt[h][0]);
    f32x4 accO[2][4] = {};
#pragma unroll
    for (int kk = 0; kk < 2; ++kk) {
        long tt[4][2];
#pragma unroll
        for (int ni = 0; ni < 4; ++ni)
#pragma unroll
            for (int s = 0; s < 2; ++s) {
                unsigned a = pbase + ((((kk * 2 + s) * 4 + ni) * 4 + g) * 128) + lr * 2;
                asm volatile("ds_read_b64_tr_b16 %0, %1" : "=v"(tt[ni][s]) : "v"(a));
            }
        asm volatile("s_waitcnt lgkmcnt(0)" ::: "memory");
        __builtin_amdgcn_sched_barrier(0);
#pragma unroll
        for (int ni = 0; ni < 4; ++ni) {
            union { int4 i4; bf16x8 v; } u;
            u.i4 = make_int4((int)tt[ni][0], (int)(tt[ni][0] >> 32),
                             (int)tt[ni][1], (int)(tt[ni][1] >> 32));
#pragma unroll
            for (int md = 0; md < 2; ++md)
                accO[md][ni] = __builtin_amdgcn_mfma_f32_16x16x32_bf16(vf[md][kk], u.v, accO[md][ni], 0, 0, 0);
        }
    }
#pragma unroll
    for (int ni = 0; ni < 4; ++ni) {
        int i = ni * 16 + lr;
        if (i < 49) {
#pragma unroll
            for (int md = 0; md < 2; ++md) {
                ushort4 ov;
                ov.x = f2bf(accO[md][ni][0]);
                ov.y = f2bf(accO[md][ni][1]);
                ov.z = f2bf(accO[md][ni][2]);
                ov.w = f2bf(accO[md][ni][3]);
                *(ushort4*)(ob + ((long)(w * 49 + i)) * 128 + h * 32 + md * 16 + g * 4) = ov;
            }
        }
    }
}

extern "C" void kernel_launch(void* const* d_in, const int* in_sizes, int n_in,
                              void* d_out, int out_size, void* d_ws, size_t ws_size,
                              hipStream_t stream) {
    const float* x      = (const float*)d_in[0];
    const float* n1g    = (const float*)d_in[1];
    const float* n1b    = (const float*)d_in[2];
    const float* qkv_w  = (const float*)d_in[3];
    const float* qkv_b  = (const float*)d_in[4];
    const float* proj_w = (const float*)d_in[5];
    const float* proj_b = (const float*)d_in[6];
    const float* rpb    = (const float*)d_in[7];
    const float* n2g    = (const float*)d_in[8];
    const float* n2b    = (const float*)d_in[9];
    const float* fc1_w  = (const float*)d_in[10];
    const float* fc1_b  = (const float*)d_in[11];
    const float* fc2_w  = (const float*)d_in[12];
    const float* fc2_b  = (const float*)d_in[13];
    float* out = (float*)d_out;

    // Workspace (~324 MB):
    //  [0,SZ)             hnorm -> o
    //  [SZ,3SZ+VT)        q | k | v^T
    //  [3SZ+VT, 4SZ+VT)   x2b bf16
    //  [4SZ+VT, 5SZ+VT)   h2n
    //  [5SZ+VT, ..)       weights bf16 (384KB) + biasd (64KB)
    char* ws = (char*)d_ws;
    const size_t SZ = (size_t)M * C * 2;                    // 51,380,224
    const size_t VT = (size_t)NWIN * NH * 32 * 64 * 2;      // 67,108,864
    unsigned short* hnorm  = (unsigned short*)(ws);
    unsigned short* qkvbuf = (unsigned short*)(ws + SZ);
    unsigned short* o      = hnorm;
    unsigned short* x2b    = (unsigned short*)(ws + 3 * SZ + VT);
    unsigned short* h2n    = (unsigned short*)(ws + 4 * SZ + VT);
    unsigned short* wb     = (unsigned short*)(ws + 5 * SZ + VT);
    float* biasd           = (float*)(ws + 5 * SZ + VT + 393216);
    unsigned short* wqkv = wb, *wproj = wb + 49152, *wfc1 = wb + 65536, *wfc2 = wb + 131072;

    wconv_kernel<<<768, 256, 0, stream>>>(qkv_w, proj_w, fc1_w, fc2_w, rpb, biasd, wb);
    ln_kernel<<<M / 4, 256, 0, stream>>>(x, n1g, n1b, hnorm);
    gemm_pipe<0, 128, 3, true ><<<M / 128, 256, 0, stream>>>(hnorm, wqkv, qkv_b, nullptr, nullptr, nullptr, nullptr, nullptr, qkvbuf, nullptr);
    attn_mfma<<<NWIN, 256, 0, stream>>>(qkvbuf, qkvbuf + (size_t)M * 128, qkvbuf + 2 * (size_t)M * 128, biasd, o);
    gemm_pipe<1, 128, 1, false><<<M / 128, 256, 0, stream>>>(o, wproj, proj_b, x, nullptr, n2g, n2b, nullptr, h2n, x2b);
    mlp_fused<<<M / 64, 256, 0, stream>>>(h2n, wfc1, wfc2, fc1_b, fc2_b, x2b, out);
}

// Round 11
// 402.689 us; speedup vs baseline: 1.2552x; 1.0823x over previous
//
#include <hip/hip_runtime.h>
#include <stdint.h>

// Swin block: B=64, H=W=56, C=128, HID=512, WS=7, NH=4, SHIFT=3
static constexpr int Bz   = 64;
static constexpr int HH   = 56, WWp = 56;
static constexpr int C    = 128, HID = 512;
static constexpr int L    = HH * WWp;        // 3136
static constexpr int M    = Bz * L;          // 200704
static constexpr int NWIN = Bz * 64;         // 4096 windows
static constexpr int NH   = 4;
static constexpr int SHIFT = 3;

typedef __bf16 bf16x8 __attribute__((ext_vector_type(8)));
typedef float  f32x4  __attribute__((ext_vector_type(4)));

__device__ __forceinline__ float bf2f(unsigned short u) {
    return __uint_as_float(((unsigned int)u) << 16);
}
__device__ __forceinline__ unsigned short f2bf(float f) {
    unsigned int u = __float_as_uint(f);
    return (unsigned short)((u + 0x7FFFu + ((u >> 16) & 1u)) >> 16);
}
__device__ __forceinline__ unsigned lds_addr(const void* p) {
    return (unsigned)(size_t)(__attribute__((address_space(3))) const char*)p;
}
// tanh-form gelu, one v_exp; max |dev| from exact erf-gelu ~7e-4.
__device__ __forceinline__ float gelu_f(float x) {
    float y2 = 1.5957691216057308f * (x + 0.044715f * x * x * x);
    float e  = __expf(y2);
    float t  = 1.0f - 2.0f / (e + 1.0f);
    return 0.5f * x * (1.0f + t);
}

// window-order row m -> original (b,l) row: roll(-SHIFT) + 7x7 partition.
__device__ __forceinline__ int win2orig(int m) {
    int w = m / 49, t = m - w * 49;
    int b = w >> 6, wi = (w >> 3) & 7, wj = w & 7;
    int ti = t / 7, tj = t - ti * 7;
    int i = wi * 7 + ti + SHIFT; if (i >= HH) i -= HH;
    int j = wj * 7 + tj + SHIFT; if (j >= WWp) j -= WWp;
    return b * L + i * WWp + j;
}

__device__ __forceinline__ void async_copy16(void* ldsdst, const void* gsrc) {
    __builtin_amdgcn_global_load_lds(
        (const __attribute__((address_space(1))) unsigned int*)gsrc,
        (__attribute__((address_space(3))) unsigned int*)ldsdst,
        16, 0, 0);
}

// Weights fp32->bf16 (196608 elems) + bias fragment table (16384 floats).
// biasd layout: [h][lane][mi][ni][r]; -1e30 for j>=49, 0 for i>=49.
__global__ __launch_bounds__(256) void wconv_kernel(
    const float* __restrict__ qkvw, const float* __restrict__ projw,
    const float* __restrict__ fc1w, const float* __restrict__ fc2w,
    const float* __restrict__ rpb, float* __restrict__ biasd,
    unsigned short* __restrict__ wb) {
    int i = blockIdx.x * 256 + threadIdx.x;
    float v;
    if (i < 49152)       v = qkvw[i];
    else if (i < 65536)  v = projw[i - 49152];
    else if (i < 131072) v = fc1w[i - 65536];
    else                 v = fc2w[i - 131072];
    wb[i] = f2bf(v);
    if (i < 16384) {
        int h = i >> 12, l = (i >> 6) & 63, f = i & 63;
        int mi = f >> 4, ni = (f >> 2) & 3, r = f & 3;
        int ii = mi * 16 + (l >> 4) * 4 + r;
        int jj = ni * 16 + (l & 15);
        float bv;
        if (jj >= 49)      bv = -1e30f;
        else if (ii >= 49) bv = 0.f;
        else {
            int yi = ii / 7, xi = ii - yi * 7, yj = jj / 7, xj = jj - yj * 7;
            bv = rpb[((yi - yj + 6) * 13 + (xi - xj + 6)) * NH + h];
        }
        biasd[i] = bv;
    }
}

// LayerNorm over C=128, fp32 in -> bf16 out. 1 wave/row, 4 rows/block.
__global__ __launch_bounds__(256) void ln_kernel(const float* __restrict__ in,
                                                 const float* __restrict__ g,
                                                 const float* __restrict__ bta,
                                                 unsigned short* __restrict__ out) {
    int row  = blockIdx.x * 4 + (threadIdx.x >> 6);
    int lane = threadIdx.x & 63;
    const float2 v = ((const float2*)(in + (long)row * C))[lane];
    float s  = v.x + v.y;
    float ss = v.x * v.x + v.y * v.y;
#pragma unroll
    for (int off = 32; off >= 1; off >>= 1) {
        s  += __shfl_xor(s, off);
        ss += __shfl_xor(ss, off);
    }
    float mu  = s * (1.0f / C);
    float var = ss * (1.0f / C) - mu * mu;
    float rs  = rsqrtf(var + 1e-5f);
    float2 gg = ((const float2*)g)[lane];
    float2 bb = ((const float2*)bta)[lane];
    ushort2 o;
    o.x = f2bf((v.x - mu) * rs * gg.x + bb.x);
    o.y = f2bf((v.y - mu) * rs * gg.y + bb.y);
    ((ushort2*)(out + (long)row * C))[lane] = o;
}

// Pipelined LDS-staged MFMA NT GEMM, operand-swapped (proven round 6).
// Only MODE 1 used now: proj (+ resid fp32 x; fused LN2 -> x2b AND h2n).
template<int MODE, int K, int NB, bool GATHER>
__global__ __launch_bounds__(256) void gemm_pipe(
    const unsigned short* __restrict__ A,
    const unsigned short* __restrict__ Wb,
    const float* __restrict__ bias,
    const float* __restrict__ residf,
    const unsigned short* __restrict__ residb,
    const float* __restrict__ g2, const float* __restrict__ b2,
    float* __restrict__ outf,
    unsigned short* __restrict__ outb,
    unsigned short* __restrict__ outb2)
{
    constexpr int KH = K / 64;
    constexpr bool BIGK = (K > 128);
    __shared__ char lds[65536];
    char* ldsA = lds;
    char* ldsB = lds + 32768;
    const int tid = threadIdx.x;
    const int wid = tid >> 6, lane = tid & 63;
    const int g = lane >> 4, lr = lane & 15;
    const int wm = wid >> 1, wn = wid & 1;
    const int mbase = blockIdx.x * 128;

    auto stageAfull = [&]() {
#pragma unroll
        for (int i = 0; i < 8; ++i) {
            const int c = i * 4 + wid;
            const int r = (c << 2) + (lane >> 4);
            const int s = (lane & 15) ^ (r & 15);
            long arow = GATHER ? (long)win2orig(mbase + r) : (long)(mbase + r);
            async_copy16(ldsA + c * 1024, (const char*)A + arow * (K * 2) + s * 16);
        }
    };
    auto stageBhalf = [&](int buf, int nb, int kh) {
#pragma unroll
        for (int i = 0; i < 4; ++i) {
            const int c = i * 4 + wid;
            const int r = (c << 3) + (lane >> 3);
            const int s = (lane & 7) ^ (r & 7);
            async_copy16(ldsB + buf * 16384 + c * 1024,
                         (const char*)Wb + (long)(nb * 128 + r) * (K * 2) + kh * 128 + s * 16);
        }
    };

    stageAfull();
    stageBhalf(0, 0, 0);
    __syncthreads();
    int cur = 0;

    for (int nb = 0; nb < NB; ++nb) {
        f32x4 acc[4][4] = {};
        for (int kh = 0; kh < KH; ++kh) {
            const bool last = (nb == NB - 1) && (kh == KH - 1);
            if (!last) {
                const int nnb = (kh == KH - 1) ? nb + 1 : nb;
                const int nkh = (kh == KH - 1) ? 0 : kh + 1;
                stageBhalf(cur ^ 1, nnb, nkh);
            }
#pragma unroll
            for (int kkh = 0; kkh < 2; ++kkh) {
                bf16x8 af[4], bfr[4];
#pragma unroll
                for (int mi = 0; mi < 4; ++mi) {
                    const int ra = wm * 64 + mi * 16 + lr;
                    const int kk = kh * 2 + kkh;
                    af[mi] = *(const bf16x8*)(ldsA + ra * 256 + (((kk * 4 + g) ^ (ra & 15)) * 16));
                }
#pragma unroll
                for (int ni = 0; ni < 4; ++ni) {
                    const int rb = wn * 64 + ni * 16 + lr;
                    bfr[ni] = *(const bf16x8*)(ldsB + cur * 16384 + rb * 128 + (((kkh * 4 + g) ^ (rb & 7)) * 16));
                }
#pragma unroll
                for (int mi = 0; mi < 4; ++mi)
#pragma unroll
                    for (int ni = 0; ni < 4; ++ni)
                        acc[mi][ni] = __builtin_amdgcn_mfma_f32_16x16x32_bf16(bfr[ni], af[mi], acc[mi][ni], 0, 0, 0);
            }
            if (!last) { __syncthreads(); cur ^= 1; }
        }

        // MODE 1 epilogue: x2 = x + (o@W + b); LN2 in-register (NB==1).
        int rr[4];
#pragma unroll
        for (int mi = 0; mi < 4; ++mi)
            rr[mi] = win2orig(mbase + wm * 64 + mi * 16 + lr);
#pragma unroll
        for (int mi = 0; mi < 4; ++mi)
#pragma unroll
            for (int ni = 0; ni < 4; ++ni) {
                const int nloc = wn * 64 + ni * 16 + g * 4;
                const f32x4 b4 = *(const f32x4*)&bias[nloc];
                const f32x4 r4 = *(const f32x4*)&residf[(long)rr[mi] * C + nloc];
                acc[mi][ni] += b4 + r4;
            }
        float sA[4], qA[4];
#pragma unroll
        for (int mi = 0; mi < 4; ++mi) {
            float s = 0.f, q = 0.f;
#pragma unroll
            for (int ni = 0; ni < 4; ++ni)
#pragma unroll
                for (int rg = 0; rg < 4; ++rg) {
                    float v = acc[mi][ni][rg];
                    s += v; q += v * v;
                }
            s += __shfl_xor(s, 16); q += __shfl_xor(q, 16);
            s += __shfl_xor(s, 32); q += __shfl_xor(q, 32);
            sA[mi] = s; qA[mi] = q;
        }
        float* lp = (float*)lds;
        __syncthreads();
        if (g == 0) {
#pragma unroll
            for (int mi = 0; mi < 4; ++mi) {
                int r64 = mi * 16 + lr;
                lp[((wm * 64 + r64) * 2 + wn) * 2 + 0] = sA[mi];
                lp[((wm * 64 + r64) * 2 + wn) * 2 + 1] = qA[mi];
            }
        }
        __syncthreads();
#pragma unroll
        for (int mi = 0; mi < 4; ++mi) {
            const int r64 = mi * 16 + lr;
            const float st = sA[mi] + lp[((wm * 64 + r64) * 2 + (wn ^ 1)) * 2 + 0];
            const float qt = qA[mi] + lp[((wm * 64 + r64) * 2 + (wn ^ 1)) * 2 + 1];
            const float mu = st * (1.0f / C);
            const float var = qt * (1.0f / C) - mu * mu;
            const float rs = rsqrtf(var + 1e-5f);
            const long rbase = (long)rr[mi] * C;
#pragma unroll
            for (int ni = 0; ni < 4; ++ni) {
                const int nloc = wn * 64 + ni * 16 + g * 4;
                ushort4 px, ph;
#pragma unroll
                for (int rg = 0; rg < 4; ++rg) {
                    const float xv = acc[mi][ni][rg];
                    const float hv = (xv - mu) * rs * g2[nloc + rg] + b2[nloc + rg];
                    ((unsigned short*)&px)[rg] = f2bf(xv);
                    ((unsigned short*)&ph)[rg] = f2bf(hv);
                }
                *(ushort4*)(outb2 + rbase + nloc) = px;
                *(ushort4*)(outb  + rbase + nloc) = ph;
            }
        }
    }
}

// Fused qkv+attention: 1 block/window, 1 wave/head.
// Phase A: stage hnorm window tile (64 rows x 256B, slot^(row&15) swizzle).
// Phase B (wave h): q,k = hnorm @ Wqk^T SWAPPED (thread holds 4 consecutive d)
//   -> 8B vector writes to per-head LDS q[64][32], k[64][32] (q pre-scaled).
// Phase C: v = hnorm @ Wv^T NORMAL (thread holds 4 consecutive t)
//   -> barrier (hnorm dead) -> 8B writes to v^T[32][64], slot^(d&7) swizzle.
// Phase D: attention per head exactly as proven attn_mfma, q/k/v from LDS;
//   Pt aliases q|k (8KB/head, qf/kf in regs first). All wave-private.
// LDS 48KB -> 3 blocks/CU. W frags direct from L2 (96KB resident).
__global__ __launch_bounds__(256, 3) void qkv_attn(
    const unsigned short* __restrict__ hn,   // [M][128] bf16 (orig rows)
    const unsigned short* __restrict__ Wqkv, // [384][128] bf16
    const float* __restrict__ qvb,           // [384]
    const float* __restrict__ biasd,         // [h][lane][64]
    unsigned short* __restrict__ ob)         // [w*49+t][128]
{
    __shared__ __align__(16) char reg1[16384];   // hnorm tile -> v^T (4x4KB)
    __shared__ __align__(16) char reg2[32768];   // q|k per head -> Pt
    const int tid  = threadIdx.x;
    const int h    = tid >> 6;
    const int lane = tid & 63;
    const int g    = lane >> 4, lr = lane & 15;
    const int w    = blockIdx.x;

    // ---- Phase A: stage hnorm tile (rows >=49 fold to valid rows) ----
#pragma unroll
    for (int rnd = 0; rnd < 4; ++rnd) {
        const int cb  = rnd * 4 + h;             // 1KB unit = 4 rows
        const int row = cb * 4 + g;
        const int t   = (row < 49) ? row : row - 49;
        const int s   = lr ^ (row & 15);
        const long ar = win2orig(w * 49 + t);
        async_copy16(reg1 + cb * 1024, (const char*)hn + ar * 256 + s * 16);
    }
    __syncthreads();

    // ---- Phase B: q,k GEMM (SWAPPED: mfma(wf, af)) ----
    const unsigned short* Wq = Wqkv + (long)(h * 32) * 128;
    const unsigned short* Wk = Wqkv + (long)(128 + h * 32) * 128;
    f32x4 aqk[4][4] = {};    // [nf: q0,q1,k0,k1][mi]
#pragma unroll
    for (int kk = 0; kk < 4; ++kk) {
        bf16x8 af[4], wf[4];
#pragma unroll
        for (int mi = 0; mi < 4; ++mi)
            af[mi] = *(const bf16x8*)(reg1 + (mi * 16 + lr) * 256 + (((kk * 4 + g) ^ lr) * 16));
        wf[0] = *(const bf16x8*)(Wq + (long)lr * 128 + kk * 32 + g * 8);
        wf[1] = *(const bf16x8*)(Wq + (long)(16 + lr) * 128 + kk * 32 + g * 8);
        wf[2] = *(const bf16x8*)(Wk + (long)lr * 128 + kk * 32 + g * 8);
        wf[3] = *(const bf16x8*)(Wk + (long)(16 + lr) * 128 + kk * 32 + g * 8);
#pragma unroll
        for (int nf = 0; nf < 4; ++nf)
#pragma unroll
            for (int mi = 0; mi < 4; ++mi)
                aqk[nf][mi] = __builtin_amdgcn_mfma_f32_16x16x32_bf16(wf[nf], af[mi], aqk[nf][mi], 0, 0, 0);
    }
    // write q (scaled) and k: q[t][d] rows 64B; thread has 4 consecutive d
    char* qlds = reg2 + h * 8192;
    char* klds = qlds + 4096;
    const float scale = 0.17677669529663687f;  // 1/sqrt(32)
#pragma unroll
    for (int nf = 0; nf < 4; ++nf) {
        const bool isq = (nf < 2);
        const int d0 = (nf & 1) * 16 + g * 4;
        const f32x4 b4 = *(const f32x4*)&qvb[(isq ? 0 : 128) + h * 32 + d0];
        char* dst = isq ? qlds : klds;
#pragma unroll
        for (int mi = 0; mi < 4; ++mi) {
            const int t = mi * 16 + lr;
            ushort4 pw;
#pragma unroll
            for (int rg = 0; rg < 4; ++rg) {
                float v = aqk[nf][mi][rg] + b4[rg];
                ((unsigned short*)&pw)[rg] = f2bf(isq ? v * scale : v);
            }
            *(ushort4*)(dst + t * 64 + d0 * 2) = pw;
        }
    }

    // ---- Phase C: v GEMM (NORMAL: mfma(af, wf)) ----
    const unsigned short* Wv = Wqkv + (long)(256 + h * 32) * 128;
    f32x4 av[2][4] = {};     // [nf][mi]
#pragma unroll
    for (int kk = 0; kk < 4; ++kk) {
        bf16x8 af[4], wf[2];
#pragma unroll
        for (int mi = 0; mi < 4; ++mi)
            af[mi] = *(const bf16x8*)(reg1 + (mi * 16 + lr) * 256 + (((kk * 4 + g) ^ lr) * 16));
        wf[0] = *(const bf16x8*)(Wv + (long)lr * 128 + kk * 32 + g * 8);
        wf[1] = *(const bf16x8*)(Wv + (long)(16 + lr) * 128 + kk * 32 + g * 8);
#pragma unroll
        for (int nf = 0; nf < 2; ++nf)
#pragma unroll
            for (int mi = 0; mi < 4; ++mi)
                av[nf][mi] = __builtin_amdgcn_mfma_f32_16x16x32_bf16(af[mi], wf[nf], av[nf][mi], 0, 0, 0);
    }
    __syncthreads();   // ALL waves done reading hnorm tile
    // write v^T [32 d][64 t], 128B rows, slot^(d&7); thread has 4 consec t
    char* vlds = reg1 + h * 4096;
#pragma unroll
    for (int nf = 0; nf < 2; ++nf) {
        const int d = nf * 16 + lr;
        const float bv = qvb[256 + h * 32 + d];
#pragma unroll
        for (int mi = 0; mi < 4; ++mi) {
            const int t0 = mi * 16 + g * 4;
            ushort4 pw;
#pragma unroll
            for (int rg = 0; rg < 4; ++rg)
                ((unsigned short*)&pw)[rg] = f2bf(av[nf][mi][rg] + bv);
            const int slot = t0 >> 3;
            *(ushort4*)(vlds + d * 128 + ((slot ^ (d & 7)) * 16) + (g & 1) * 8) = pw;
        }
    }

    // ---- Phase D: attention (all wave-private; proven attn_mfma body) ----
    bf16x8 qf[4], kf[4];
#pragma unroll
    for (int mi = 0; mi < 4; ++mi) {
        qf[mi] = *(const bf16x8*)(qlds + (mi * 16 + lr) * 64 + g * 16);
        kf[mi] = *(const bf16x8*)(klds + (mi * 16 + lr) * 64 + g * 16);
    }
    f32x4 acc[4][4] = {};
#pragma unroll
    for (int mi = 0; mi < 4; ++mi)
#pragma unroll
        for (int ni = 0; ni < 4; ++ni)
            acc[mi][ni] = __builtin_amdgcn_mfma_f32_16x16x32_bf16(qf[mi], kf[ni], acc[mi][ni], 0, 0, 0);

    const float* bp = biasd + (h * 64 + lane) * 64;
    char* ptw = reg2 + h * 8192;   // Pt overwrites q|k (qf/kf already in regs)
#pragma unroll
    for (int mi = 0; mi < 4; ++mi) {
#pragma unroll
        for (int ni = 0; ni < 4; ++ni)
            acc[mi][ni] += *(const f32x4*)(bp + mi * 16 + ni * 4);
#pragma unroll
        for (int c = 0; c < 4; ++c)
            acc[mi][3][c] = (lr == 0) ? acc[mi][3][c] : -1e30f;
        f32x4 mx;
#pragma unroll
        for (int c = 0; c < 4; ++c)
            mx[c] = fmaxf(fmaxf(acc[mi][0][c], acc[mi][1][c]), fmaxf(acc[mi][2][c], acc[mi][3][c]));
#pragma unroll
        for (int off = 1; off <= 8; off <<= 1)
#pragma unroll
            for (int c = 0; c < 4; ++c)
                mx[c] = fmaxf(mx[c], __shfl_xor(mx[c], off));
        f32x4 sum = {};
#pragma unroll
        for (int ni = 0; ni < 4; ++ni)
#pragma unroll
            for (int c = 0; c < 4; ++c) {
                float e = __expf(acc[mi][ni][c] - mx[c]);
                acc[mi][ni][c] = e;
                sum[c] += e;
            }
#pragma unroll
        for (int off = 1; off <= 8; off <<= 1)
#pragma unroll
            for (int c = 0; c < 4; ++c)
                sum[c] += __shfl_xor(sum[c], off);
        f32x4 inv;
#pragma unroll
        for (int c = 0; c < 4; ++c)
            inv[c] = __builtin_amdgcn_rcpf(sum[c]);
#pragma unroll
        for (int ni = 0; ni < 4; ++ni) {
            ushort4 pw;
            pw.x = f2bf(acc[mi][ni][0] * inv[0]);
            pw.y = f2bf(acc[mi][ni][1] * inv[1]);
            pw.z = f2bf(acc[mi][ni][2] * inv[2]);
            pw.w = f2bf(acc[mi][ni][3] * inv[3]);
            int jb  = ni * 4 + (lr >> 2);
            int tix = (((jb >> 3) * 2 + (jb & 1)) * 4 + mi) * 4 + ((jb >> 1) & 3);
            *(ushort4*)(ptw + tix * 128 + (lr & 3) * 32 + g * 8) = pw;
        }
    }
    asm volatile("s_waitcnt lgkmcnt(0)" ::: "memory");  // Pt/v writes landed

    // v^T A-frags from LDS (swizzled reads)
    bf16x8 vf[2][2];
#pragma unroll
    for (int md = 0; md < 2; ++md)
#pragma unroll
        for (int kk = 0; kk < 2; ++kk)
            vf[md][kk] = *(const bf16x8*)(vlds + (md * 16 + lr) * 128 + (((kk * 4 + g) ^ (lr & 7)) * 16));

    const unsigned pbase = lds_addr(ptw);
    f32x4 accO[2][4] = {};
#pragma unroll
    for (int kk = 0; kk < 2; ++kk) {
        long tt[4][2];
#pragma unroll
        for (int ni = 0; ni < 4; ++ni)
#pragma unroll
            for (int s = 0; s < 2; ++s) {
                unsigned a = pbase + ((((kk * 2 + s) * 4 + ni) * 4 + g) * 128) + lr * 2;
                asm volatile("ds_read_b64_tr_b16 %0, %1" : "=v"(tt[ni][s]) : "v"(a));
            }
        asm volatile("s_waitcnt lgkmcnt(0)" ::: "memory");
        __builtin_amdgcn_sched_barrier(0);
#pragma unroll
        for (int ni = 0; ni < 4; ++ni) {
            union { int4 i4; bf16x8 v; } u;
            u.i4 = make_int4((int)tt[ni][0], (int)(tt[ni][0] >> 32),
                             (int)tt[ni][1], (int)(tt[ni][1] >> 32));
#pragma unroll
            for (int md = 0; md < 2; ++md)
                accO[md][ni] = __builtin_amdgcn_mfma_f32_16x16x32_bf16(vf[md][kk], u.v, accO[md][ni], 0, 0, 0);
        }
    }
#pragma unroll
    for (int ni = 0; ni < 4; ++ni) {
        int i = ni * 16 + lr;
        if (i < 49) {
#pragma unroll
            for (int md = 0; md < 2; ++md) {
                ushort4 ov;
                ov.x = f2bf(accO[md][ni][0]);
                ov.y = f2bf(accO[md][ni][1]);
                ov.z = f2bf(accO[md][ni][2]);
                ov.w = f2bf(accO[md][ni][3]);
                *(ushort4*)(ob + ((long)(w * 49 + i)) * 128 + h * 32 + md * 16 + g * 4) = ov;
            }
        }
    }
}

// Fused MLP v4 (unchanged from round 10 best).
__global__ __launch_bounds__(256, 3) void mlp_fused(
    const unsigned short* __restrict__ A,     // h2n [M][128] bf16
    const unsigned short* __restrict__ W1,    // [512][128] bf16
    const unsigned short* __restrict__ W2,    // [128][512] bf16
    const float* __restrict__ b1,             // [512]
    const float* __restrict__ b2,             // [128]
    const unsigned short* __restrict__ resid, // x2b [M][128] bf16
    float* __restrict__ out)                  // [M][128] fp32
{
    __shared__ char ldsW[32768];
    __shared__ char ldsP[16384];
    const int tid = threadIdx.x;
    const int wid = tid >> 6, lane = tid & 63;
    const int g = lane >> 4, lr = lane & 15;
    const int wm = wid >> 1, wn = wid & 1;
    const int mbase = blockIdx.x * 64;

    bf16x8 af[2][4];
#pragma unroll
    for (int mi = 0; mi < 2; ++mi) {
        const long rb = (long)(mbase + wm * 32 + mi * 16 + lr) * 128;
#pragma unroll
        for (int kk = 0; kk < 4; ++kk)
            af[mi][kk] = *(const bf16x8*)(A + rb + kk * 32 + g * 8);
    }

    auto stageW1 = [&](int c) {
#pragma unroll
        for (int i = 0; i < 8; ++i) {
            const int cb = i * 4 + wid;
            const int r  = cb * 4 + g;
            const int s  = lr ^ (r & 15);
            async_copy16(ldsW + cb * 1024, (const char*)W1 + (long)(c * 128 + r) * 256 + s * 16);
        }
    };

    stageW1(0);
    f32x4 oacc[2][4] = {};

    for (int c = 0; c < 4; ++c) {
        __syncthreads();
#pragma unroll
        for (int hh = 0; hh < 2; ++hh) {
            f32x4 pacc[2][2] = {};
#pragma unroll
            for (int kk = 0; kk < 4; ++kk) {
                bf16x8 w1f[2];
#pragma unroll
                for (int ni = 0; ni < 2; ++ni) {
                    const int rb = hh * 64 + wn * 32 + ni * 16 + lr;
                    w1f[ni] = *(const bf16x8*)(ldsW + rb * 256 + (((kk * 4 + g) ^ (rb & 15)) * 16));
                }
#pragma unroll
                for (int mi = 0; mi < 2; ++mi)
#pragma unroll
                    for (int ni = 0; ni < 2; ++ni)
                        pacc[mi][ni] = __builtin_amdgcn_mfma_f32_16x16x32_bf16(w1f[ni], af[mi][kk], pacc[mi][ni], 0, 0, 0);
            }
#pragma unroll
            for (int mi = 0; mi < 2; ++mi) {
                const int m = wm * 32 + mi * 16 + lr;
#pragma unroll
                for (int ni = 0; ni < 2; ++ni) {
                    const int h0 = hh * 64 + wn * 32 + ni * 16 + g * 4;
                    const f32x4 b4 = *(const f32x4*)&b1[c * 128 + h0];
                    ushort4 pw;
                    pw.x = f2bf(gelu_f(pacc[mi][ni][0] + b4[0]));
                    pw.y = f2bf(gelu_f(pacc[mi][ni][1] + b4[1]));
                    pw.z = f2bf(gelu_f(pacc[mi][ni][2] + b4[2]));
                    pw.w = f2bf(gelu_f(pacc[mi][ni][3] + b4[3]));
                    *(ushort4*)(ldsP + m * 256 + (((h0 >> 3) ^ (m & 15)) * 16) + (g & 1) * 8) = pw;
                }
            }
        }
        __syncthreads();
        if (c < 3) stageW1(c + 1);
#pragma unroll
        for (int kk = 0; kk < 4; ++kk) {
            bf16x8 pf[2], w2f[4];
#pragma unroll
            for (int mi = 0; mi < 2; ++mi) {
                const int ra = wm * 32 + mi * 16 + lr;
                pf[mi] = *(const bf16x8*)(ldsP + ra * 256 + (((kk * 4 + g) ^ (ra & 15)) * 16));
            }
#pragma unroll
            for (int ni = 0; ni < 4; ++ni)
                w2f[ni] = *(const bf16x8*)(W2 + (long)(wn * 64 + ni * 16 + lr) * 512 + c * 128 + kk * 32 + g * 8);
#pragma unroll
            for (int mi = 0; mi < 2; ++mi)
#pragma unroll
                for (int ni = 0; ni < 4; ++ni)
                    oacc[mi][ni] = __builtin_amdgcn_mfma_f32_16x16x32_bf16(w2f[ni], pf[mi], oacc[mi][ni], 0, 0, 0);
        }
    }

#pragma unroll
    for (int mi = 0; mi < 2; ++mi) {
        const long gm = mbase + wm * 32 + mi * 16 + lr;
#pragma unroll
        for (int ni = 0; ni < 4; ++ni) {
            const int n0 = wn * 64 + ni * 16 + g * 4;
            const f32x4 b4 = *(const f32x4*)&b2[n0];
            const ushort4 r4 = *(const ushort4*)(resid + gm * C + n0);
            f32x4 o4;
            o4[0] = oacc[mi][ni][0] + b4[0] + bf2f(r4.x);
            o4[1] = oacc[mi][ni][1] + b4[1] + bf2f(r4.y);
            o4[2] = oacc[mi][ni][2] + b4[2] + bf2f(r4.z);
            o4[3] = oacc[mi][ni][3] + b4[3] + bf2f(r4.w);
            *(f32x4*)(out + gm * C + n0) = o4;
        }
    }
}

extern "C" void kernel_launch(void* const* d_in, const int* in_sizes, int n_in,
                              void* d_out, int out_size, void* d_ws, size_t ws_size,
                              hipStream_t stream) {
    const float* x      = (const float*)d_in[0];
    const float* n1g    = (const float*)d_in[1];
    const float* n1b    = (const float*)d_in[2];
    const float* qkv_w  = (const float*)d_in[3];
    const float* qkv_b  = (const float*)d_in[4];
    const float* proj_w = (const float*)d_in[5];
    const float* proj_b = (const float*)d_in[6];
    const float* rpb    = (const float*)d_in[7];
    const float* n2g    = (const float*)d_in[8];
    const float* n2b    = (const float*)d_in[9];
    const float* fc1_w  = (const float*)d_in[10];
    const float* fc1_b  = (const float*)d_in[11];
    const float* fc2_w  = (const float*)d_in[12];
    const float* fc2_b  = (const float*)d_in[13];
    float* out = (float*)d_out;

    // Workspace (~206 MB):
    //  [0,SZ)       hnorm bf16
    //  [SZ,2SZ)     o bf16 (window-order rows)
    //  [2SZ,3SZ)    x2b bf16
    //  [3SZ,4SZ)    h2n bf16
    //  [4SZ,..)     weights bf16 (384KB) + biasd (64KB)
    char* ws = (char*)d_ws;
    const size_t SZ = (size_t)M * C * 2;                    // 51,380,224
    unsigned short* hnorm = (unsigned short*)(ws);
    unsigned short* o     = (unsigned short*)(ws + SZ);
    unsigned short* x2b   = (unsigned short*)(ws + 2 * SZ);
    unsigned short* h2n   = (unsigned short*)(ws + 3 * SZ);
    unsigned short* wb    = (unsigned short*)(ws + 4 * SZ);
    float* biasd          = (float*)(ws + 4 * SZ + 393216);
    unsigned short* wqkv = wb, *wproj = wb + 49152, *wfc1 = wb + 65536, *wfc2 = wb + 131072;

    wconv_kernel<<<768, 256, 0, stream>>>(qkv_w, proj_w, fc1_w, fc2_w, rpb, biasd, wb);
    ln_kernel<<<M / 4, 256, 0, stream>>>(x, n1g, n1b, hnorm);
    qkv_attn<<<NWIN, 256, 0, stream>>>(hnorm, wqkv, qkv_b, biasd, o);
    gemm_pipe<1, 128, 1, false><<<M / 128, 256, 0, stream>>>(o, wproj, proj_b, x, nullptr, n2g, n2b, nullptr, h2n, x2b);
    mlp_fused<<<M / 64, 256, 0, stream>>>(h2n, wfc1, wfc2, fc1_b, fc2_b, x2b, out);
}

// Round 12
// 372.492 us; speedup vs baseline: 1.3569x; 1.0811x over previous
//
#include <hip/hip_runtime.h>
#include <stdint.h>

// Swin block: B=64, H=W=56, C=128, HID=512, WS=7, NH=4, SHIFT=3
static constexpr int Bz   = 64;
static constexpr int HH   = 56, WWp = 56;
static constexpr int C    = 128, HID = 512;
static constexpr int L    = HH * WWp;        // 3136
static constexpr int M    = Bz * L;          // 200704
static constexpr int NWIN = Bz * 64;         // 4096 windows
static constexpr int NH   = 4;
static constexpr int SHIFT = 3;

typedef __bf16 bf16x8 __attribute__((ext_vector_type(8)));
typedef float  f32x4  __attribute__((ext_vector_type(4)));

__device__ __forceinline__ float bf2f(unsigned short u) {
    return __uint_as_float(((unsigned int)u) << 16);
}
__device__ __forceinline__ unsigned short f2bf(float f) {
    unsigned int u = __float_as_uint(f);
    return (unsigned short)((u + 0x7FFFu + ((u >> 16) & 1u)) >> 16);
}
// HW packed f32->bf16 (RNE), 1 instr per 2 values (T12; no builtin on gfx950)
__device__ __forceinline__ unsigned pkbf(float a, float b) {
    unsigned r;
    asm("v_cvt_pk_bf16_f32 %0, %1, %2" : "=v"(r) : "v"(a), "v"(b));
    return r;
}
__device__ __forceinline__ unsigned lds_addr(const void* p) {
    return (unsigned)(size_t)(__attribute__((address_space(3))) const char*)p;
}
// sigmoid-gelu: x*sigmoid(1.702x). ~5 VALU ops. |dev| from erf-gelu <=0.005
// for |x|<~1 (h2 std ~0.23 -> propagated output error ~0.003 << 0.109 thr).
__device__ __forceinline__ float gelu_s(float x) {
    float e = __expf(-1.702f * x);
    return x * __builtin_amdgcn_rcpf(1.0f + e);
}

// window-order row m -> original (b,l) row: roll(-SHIFT) + 7x7 partition.
__device__ __forceinline__ int win2orig(int m) {
    int w = m / 49, t = m - w * 49;
    int b = w >> 6, wi = (w >> 3) & 7, wj = w & 7;
    int ti = t / 7, tj = t - ti * 7;
    int i = wi * 7 + ti + SHIFT; if (i >= HH) i -= HH;
    int j = wj * 7 + tj + SHIFT; if (j >= WWp) j -= WWp;
    return b * L + i * WWp + j;
}

__device__ __forceinline__ void async_copy16(void* ldsdst, const void* gsrc) {
    __builtin_amdgcn_global_load_lds(
        (const __attribute__((address_space(1))) unsigned int*)gsrc,
        (__attribute__((address_space(3))) unsigned int*)ldsdst,
        16, 0, 0);
}

// Weights fp32->bf16 (196608 elems) + bias fragment table (16384 floats).
// biasd layout: [h][lane][mi][ni][r]; -1e30 for j>=49, 0 for i>=49.
__global__ __launch_bounds__(256) void wconv_kernel(
    const float* __restrict__ qkvw, const float* __restrict__ projw,
    const float* __restrict__ fc1w, const float* __restrict__ fc2w,
    const float* __restrict__ rpb, float* __restrict__ biasd,
    unsigned short* __restrict__ wb) {
    int i = blockIdx.x * 256 + threadIdx.x;
    float v;
    if (i < 49152)       v = qkvw[i];
    else if (i < 65536)  v = projw[i - 49152];
    else if (i < 131072) v = fc1w[i - 65536];
    else                 v = fc2w[i - 131072];
    wb[i] = f2bf(v);
    if (i < 16384) {
        int h = i >> 12, l = (i >> 6) & 63, f = i & 63;
        int mi = f >> 4, ni = (f >> 2) & 3, r = f & 3;
        int ii = mi * 16 + (l >> 4) * 4 + r;
        int jj = ni * 16 + (l & 15);
        float bv;
        if (jj >= 49)      bv = -1e30f;
        else if (ii >= 49) bv = 0.f;
        else {
            int yi = ii / 7, xi = ii - yi * 7, yj = jj / 7, xj = jj - yj * 7;
            bv = rpb[((yi - yj + 6) * 13 + (xi - xj + 6)) * NH + h];
        }
        biasd[i] = bv;
    }
}

// LayerNorm over C=128, fp32 in -> bf16 out. 1 wave/row, 4 rows/block.
__global__ __launch_bounds__(256) void ln_kernel(const float* __restrict__ in,
                                                 const float* __restrict__ g,
                                                 const float* __restrict__ bta,
                                                 unsigned short* __restrict__ out) {
    int row  = blockIdx.x * 4 + (threadIdx.x >> 6);
    int lane = threadIdx.x & 63;
    const float2 v = ((const float2*)(in + (long)row * C))[lane];
    float s  = v.x + v.y;
    float ss = v.x * v.x + v.y * v.y;
#pragma unroll
    for (int off = 32; off >= 1; off >>= 1) {
        s  += __shfl_xor(s, off);
        ss += __shfl_xor(ss, off);
    }
    float mu  = s * (1.0f / C);
    float var = ss * (1.0f / C) - mu * mu;
    float rs  = rsqrtf(var + 1e-5f);
    float2 gg = ((const float2*)g)[lane];
    float2 bb = ((const float2*)bta)[lane];
    unsigned o = pkbf((v.x - mu) * rs * gg.x + bb.x,
                      (v.y - mu) * rs * gg.y + bb.y);
    ((unsigned*)(out + (long)row * C))[lane] = o;
}

// Pipelined LDS-staged MFMA NT GEMM, operand-swapped (proven round 6).
// Only MODE 1 used now: proj (+ resid fp32 x; fused LN2 -> x2b AND h2n).
template<int MODE, int K, int NB, bool GATHER>
__global__ __launch_bounds__(256) void gemm_pipe(
    const unsigned short* __restrict__ A,
    const unsigned short* __restrict__ Wb,
    const float* __restrict__ bias,
    const float* __restrict__ residf,
    const unsigned short* __restrict__ residb,
    const float* __restrict__ g2, const float* __restrict__ b2,
    float* __restrict__ outf,
    unsigned short* __restrict__ outb,
    unsigned short* __restrict__ outb2)
{
    constexpr int KH = K / 64;
    __shared__ char lds[65536];
    char* ldsA = lds;
    char* ldsB = lds + 32768;
    const int tid = threadIdx.x;
    const int wid = tid >> 6, lane = tid & 63;
    const int g = lane >> 4, lr = lane & 15;
    const int wm = wid >> 1, wn = wid & 1;
    const int mbase = blockIdx.x * 128;

    auto stageAfull = [&]() {
#pragma unroll
        for (int i = 0; i < 8; ++i) {
            const int c = i * 4 + wid;
            const int r = (c << 2) + (lane >> 4);
            const int s = (lane & 15) ^ (r & 15);
            long arow = GATHER ? (long)win2orig(mbase + r) : (long)(mbase + r);
            async_copy16(ldsA + c * 1024, (const char*)A + arow * (K * 2) + s * 16);
        }
    };
    auto stageBhalf = [&](int buf, int nb, int kh) {
#pragma unroll
        for (int i = 0; i < 4; ++i) {
            const int c = i * 4 + wid;
            const int r = (c << 3) + (lane >> 3);
            const int s = (lane & 7) ^ (r & 7);
            async_copy16(ldsB + buf * 16384 + c * 1024,
                         (const char*)Wb + (long)(nb * 128 + r) * (K * 2) + kh * 128 + s * 16);
        }
    };

    stageAfull();
    stageBhalf(0, 0, 0);
    __syncthreads();
    int cur = 0;

    for (int nb = 0; nb < NB; ++nb) {
        f32x4 acc[4][4] = {};
        for (int kh = 0; kh < KH; ++kh) {
            const bool last = (nb == NB - 1) && (kh == KH - 1);
            if (!last) {
                const int nnb = (kh == KH - 1) ? nb + 1 : nb;
                const int nkh = (kh == KH - 1) ? 0 : kh + 1;
                stageBhalf(cur ^ 1, nnb, nkh);
            }
#pragma unroll
            for (int kkh = 0; kkh < 2; ++kkh) {
                bf16x8 af[4], bfr[4];
#pragma unroll
                for (int mi = 0; mi < 4; ++mi) {
                    const int ra = wm * 64 + mi * 16 + lr;
                    const int kk = kh * 2 + kkh;
                    af[mi] = *(const bf16x8*)(ldsA + ra * 256 + (((kk * 4 + g) ^ (ra & 15)) * 16));
                }
#pragma unroll
                for (int ni = 0; ni < 4; ++ni) {
                    const int rb = wn * 64 + ni * 16 + lr;
                    bfr[ni] = *(const bf16x8*)(ldsB + cur * 16384 + rb * 128 + (((kkh * 4 + g) ^ (rb & 7)) * 16));
                }
#pragma unroll
                for (int mi = 0; mi < 4; ++mi)
#pragma unroll
                    for (int ni = 0; ni < 4; ++ni)
                        acc[mi][ni] = __builtin_amdgcn_mfma_f32_16x16x32_bf16(bfr[ni], af[mi], acc[mi][ni], 0, 0, 0);
            }
            if (!last) { __syncthreads(); cur ^= 1; }
        }

        // MODE 1 epilogue: x2 = x + (o@W + b); LN2 in-register (NB==1).
        int rr[4];
#pragma unroll
        for (int mi = 0; mi < 4; ++mi)
            rr[mi] = win2orig(mbase + wm * 64 + mi * 16 + lr);
#pragma unroll
        for (int mi = 0; mi < 4; ++mi)
#pragma unroll
            for (int ni = 0; ni < 4; ++ni) {
                const int nloc = wn * 64 + ni * 16 + g * 4;
                const f32x4 b4 = *(const f32x4*)&bias[nloc];
                const f32x4 r4 = *(const f32x4*)&residf[(long)rr[mi] * C + nloc];
                acc[mi][ni] += b4 + r4;
            }
        float sA[4], qA[4];
#pragma unroll
        for (int mi = 0; mi < 4; ++mi) {
            float s = 0.f, q = 0.f;
#pragma unroll
            for (int ni = 0; ni < 4; ++ni)
#pragma unroll
                for (int rg = 0; rg < 4; ++rg) {
                    float v = acc[mi][ni][rg];
                    s += v; q += v * v;
                }
            s += __shfl_xor(s, 16); q += __shfl_xor(q, 16);
            s += __shfl_xor(s, 32); q += __shfl_xor(q, 32);
            sA[mi] = s; qA[mi] = q;
        }
        float* lp = (float*)lds;
        __syncthreads();
        if (g == 0) {
#pragma unroll
            for (int mi = 0; mi < 4; ++mi) {
                int r64 = mi * 16 + lr;
                lp[((wm * 64 + r64) * 2 + wn) * 2 + 0] = sA[mi];
                lp[((wm * 64 + r64) * 2 + wn) * 2 + 1] = qA[mi];
            }
        }
        __syncthreads();
#pragma unroll
        for (int mi = 0; mi < 4; ++mi) {
            const int r64 = mi * 16 + lr;
            const float st = sA[mi] + lp[((wm * 64 + r64) * 2 + (wn ^ 1)) * 2 + 0];
            const float qt = qA[mi] + lp[((wm * 64 + r64) * 2 + (wn ^ 1)) * 2 + 1];
            const float mu = st * (1.0f / C);
            const float var = qt * (1.0f / C) - mu * mu;
            const float rs = rsqrtf(var + 1e-5f);
            const long rbase = (long)rr[mi] * C;
#pragma unroll
            for (int ni = 0; ni < 4; ++ni) {
                const int nloc = wn * 64 + ni * 16 + g * 4;
                float xv[4], hv[4];
#pragma unroll
                for (int rg = 0; rg < 4; ++rg) {
                    xv[rg] = acc[mi][ni][rg];
                    hv[rg] = (xv[rg] - mu) * rs * g2[nloc + rg] + b2[nloc + rg];
                }
                *(uint2*)(outb2 + rbase + nloc) = make_uint2(pkbf(xv[0], xv[1]), pkbf(xv[2], xv[3]));
                *(uint2*)(outb  + rbase + nloc) = make_uint2(pkbf(hv[0], hv[1]), pkbf(hv[2], hv[3]));
            }
        }
    }
}

// Fused qkv+attention: 1 block/window, 1 wave/head (proven round 11).
__global__ __launch_bounds__(256, 3) void qkv_attn(
    const unsigned short* __restrict__ hn,   // [M][128] bf16 (orig rows)
    const unsigned short* __restrict__ Wqkv, // [384][128] bf16
    const float* __restrict__ qvb,           // [384]
    const float* __restrict__ biasd,         // [h][lane][64]
    unsigned short* __restrict__ ob)         // [w*49+t][128]
{
    __shared__ __align__(16) char reg1[16384];   // hnorm tile -> v^T (4x4KB)
    __shared__ __align__(16) char reg2[32768];   // q|k per head -> Pt
    const int tid  = threadIdx.x;
    const int h    = tid >> 6;
    const int lane = tid & 63;
    const int g    = lane >> 4, lr = lane & 15;
    const int w    = blockIdx.x;

    // ---- Phase A: stage hnorm tile (rows >=49 fold to valid rows) ----
#pragma unroll
    for (int rnd = 0; rnd < 4; ++rnd) {
        const int cb  = rnd * 4 + h;             // 1KB unit = 4 rows
        const int row = cb * 4 + g;
        const int t   = (row < 49) ? row : row - 49;
        const int s   = lr ^ (row & 15);
        const long ar = win2orig(w * 49 + t);
        async_copy16(reg1 + cb * 1024, (const char*)hn + ar * 256 + s * 16);
    }
    __syncthreads();

    // ---- Phase B: q,k GEMM (SWAPPED: mfma(wf, af)) ----
    const unsigned short* Wq = Wqkv + (long)(h * 32) * 128;
    const unsigned short* Wk = Wqkv + (long)(128 + h * 32) * 128;
    f32x4 aqk[4][4] = {};    // [nf: q0,q1,k0,k1][mi]
#pragma unroll
    for (int kk = 0; kk < 4; ++kk) {
        bf16x8 af[4], wf[4];
#pragma unroll
        for (int mi = 0; mi < 4; ++mi)
            af[mi] = *(const bf16x8*)(reg1 + (mi * 16 + lr) * 256 + (((kk * 4 + g) ^ lr) * 16));
        wf[0] = *(const bf16x8*)(Wq + (long)lr * 128 + kk * 32 + g * 8);
        wf[1] = *(const bf16x8*)(Wq + (long)(16 + lr) * 128 + kk * 32 + g * 8);
        wf[2] = *(const bf16x8*)(Wk + (long)lr * 128 + kk * 32 + g * 8);
        wf[3] = *(const bf16x8*)(Wk + (long)(16 + lr) * 128 + kk * 32 + g * 8);
#pragma unroll
        for (int nf = 0; nf < 4; ++nf)
#pragma unroll
            for (int mi = 0; mi < 4; ++mi)
                aqk[nf][mi] = __builtin_amdgcn_mfma_f32_16x16x32_bf16(wf[nf], af[mi], aqk[nf][mi], 0, 0, 0);
    }
    // write q (scaled) and k: q[t][d] rows 64B; thread has 4 consecutive d
    char* qlds = reg2 + h * 8192;
    char* klds = qlds + 4096;
    const float scale = 0.17677669529663687f;  // 1/sqrt(32)
#pragma unroll
    for (int nf = 0; nf < 4; ++nf) {
        const bool isq = (nf < 2);
        const int d0 = (nf & 1) * 16 + g * 4;
        const f32x4 b4 = *(const f32x4*)&qvb[(isq ? 0 : 128) + h * 32 + d0];
        char* dst = isq ? qlds : klds;
#pragma unroll
        for (int mi = 0; mi < 4; ++mi) {
            const int t = mi * 16 + lr;
            float v0 = aqk[nf][mi][0] + b4[0], v1 = aqk[nf][mi][1] + b4[1];
            float v2 = aqk[nf][mi][2] + b4[2], v3 = aqk[nf][mi][3] + b4[3];
            if (isq) { v0 *= scale; v1 *= scale; v2 *= scale; v3 *= scale; }
            *(uint2*)(dst + t * 64 + d0 * 2) = make_uint2(pkbf(v0, v1), pkbf(v2, v3));
        }
    }

    // ---- Phase C: v GEMM (NORMAL: mfma(af, wf)) ----
    const unsigned short* Wv = Wqkv + (long)(256 + h * 32) * 128;
    f32x4 av[2][4] = {};     // [nf][mi]
#pragma unroll
    for (int kk = 0; kk < 4; ++kk) {
        bf16x8 af[4], wf[2];
#pragma unroll
        for (int mi = 0; mi < 4; ++mi)
            af[mi] = *(const bf16x8*)(reg1 + (mi * 16 + lr) * 256 + (((kk * 4 + g) ^ lr) * 16));
        wf[0] = *(const bf16x8*)(Wv + (long)lr * 128 + kk * 32 + g * 8);
        wf[1] = *(const bf16x8*)(Wv + (long)(16 + lr) * 128 + kk * 32 + g * 8);
#pragma unroll
        for (int nf = 0; nf < 2; ++nf)
#pragma unroll
            for (int mi = 0; mi < 4; ++mi)
                av[nf][mi] = __builtin_amdgcn_mfma_f32_16x16x32_bf16(af[mi], wf[nf], av[nf][mi], 0, 0, 0);
    }
    __syncthreads();   // ALL waves done reading hnorm tile
    // write v^T [32 d][64 t], 128B rows, slot^(d&7); thread has 4 consec t
    char* vlds = reg1 + h * 4096;
#pragma unroll
    for (int nf = 0; nf < 2; ++nf) {
        const int d = nf * 16 + lr;
        const float bv = qvb[256 + h * 32 + d];
#pragma unroll
        for (int mi = 0; mi < 4; ++mi) {
            const int t0 = mi * 16 + g * 4;
            const int slot = t0 >> 3;
            *(uint2*)(vlds + d * 128 + ((slot ^ (d & 7)) * 16) + (g & 1) * 8) =
                make_uint2(pkbf(av[nf][mi][0] + bv, av[nf][mi][1] + bv),
                           pkbf(av[nf][mi][2] + bv, av[nf][mi][3] + bv));
        }
    }

    // ---- Phase D: attention (all wave-private; proven attn_mfma body) ----
    bf16x8 qf[4], kf[4];
#pragma unroll
    for (int mi = 0; mi < 4; ++mi) {
        qf[mi] = *(const bf16x8*)(qlds + (mi * 16 + lr) * 64 + g * 16);
        kf[mi] = *(const bf16x8*)(klds + (mi * 16 + lr) * 64 + g * 16);
    }
    f32x4 acc[4][4] = {};
#pragma unroll
    for (int mi = 0; mi < 4; ++mi)
#pragma unroll
        for (int ni = 0; ni < 4; ++ni)
            acc[mi][ni] = __builtin_amdgcn_mfma_f32_16x16x32_bf16(qf[mi], kf[ni], acc[mi][ni], 0, 0, 0);

    const float* bp = biasd + (h * 64 + lane) * 64;
    char* ptw = reg2 + h * 8192;   // Pt overwrites q|k (qf/kf already in regs)
#pragma unroll
    for (int mi = 0; mi < 4; ++mi) {
#pragma unroll
        for (int ni = 0; ni < 4; ++ni)
            acc[mi][ni] += *(const f32x4*)(bp + mi * 16 + ni * 4);
#pragma unroll
        for (int c = 0; c < 4; ++c)
            acc[mi][3][c] = (lr == 0) ? acc[mi][3][c] : -1e30f;
        f32x4 mx;
#pragma unroll
        for (int c = 0; c < 4; ++c)
            mx[c] = fmaxf(fmaxf(acc[mi][0][c], acc[mi][1][c]), fmaxf(acc[mi][2][c], acc[mi][3][c]));
#pragma unroll
        for (int off = 1; off <= 8; off <<= 1)
#pragma unroll
            for (int c = 0; c < 4; ++c)
                mx[c] = fmaxf(mx[c], __shfl_xor(mx[c], off));
        f32x4 sum = {};
#pragma unroll
        for (int ni = 0; ni < 4; ++ni)
#pragma unroll
            for (int c = 0; c < 4; ++c) {
                float e = __expf(acc[mi][ni][c] - mx[c]);
                acc[mi][ni][c] = e;
                sum[c] += e;
            }
#pragma unroll
        for (int off = 1; off <= 8; off <<= 1)
#pragma unroll
            for (int c = 0; c < 4; ++c)
                sum[c] += __shfl_xor(sum[c], off);
        f32x4 inv;
#pragma unroll
        for (int c = 0; c < 4; ++c)
            inv[c] = __builtin_amdgcn_rcpf(sum[c]);
#pragma unroll
        for (int ni = 0; ni < 4; ++ni) {
            int jb  = ni * 4 + (lr >> 2);
            int tix = (((jb >> 3) * 2 + (jb & 1)) * 4 + mi) * 4 + ((jb >> 1) & 3);
            *(uint2*)(ptw + tix * 128 + (lr & 3) * 32 + g * 8) =
                make_uint2(pkbf(acc[mi][ni][0] * inv[0], acc[mi][ni][1] * inv[1]),
                           pkbf(acc[mi][ni][2] * inv[2], acc[mi][ni][3] * inv[3]));
        }
    }
    asm volatile("s_waitcnt lgkmcnt(0)" ::: "memory");  // Pt/v writes landed

    // v^T A-frags from LDS (swizzled reads)
    bf16x8 vf[2][2];
#pragma unroll
    for (int md = 0; md < 2; ++md)
#pragma unroll
        for (int kk = 0; kk < 2; ++kk)
            vf[md][kk] = *(const bf16x8*)(vlds + (md * 16 + lr) * 128 + (((kk * 4 + g) ^ (lr & 7)) * 16));

    const unsigned pbase = lds_addr(ptw);
    f32x4 accO[2][4] = {};
#pragma unroll
    for (int kk = 0; kk < 2; ++kk) {
        long tt[4][2];
#pragma unroll
        for (int ni = 0; ni < 4; ++ni)
#pragma unroll
            for (int s = 0; s < 2; ++s) {
                unsigned a = pbase + ((((kk * 2 + s) * 4 + ni) * 4 + g) * 128) + lr * 2;
                asm volatile("ds_read_b64_tr_b16 %0, %1" : "=v"(tt[ni][s]) : "v"(a));
            }
        asm volatile("s_waitcnt lgkmcnt(0)" ::: "memory");
        __builtin_amdgcn_sched_barrier(0);
#pragma unroll
        for (int ni = 0; ni < 4; ++ni) {
            union { int4 i4; bf16x8 v; } u;
            u.i4 = make_int4((int)tt[ni][0], (int)(tt[ni][0] >> 32),
                             (int)tt[ni][1], (int)(tt[ni][1] >> 32));
#pragma unroll
            for (int md = 0; md < 2; ++md)
                accO[md][ni] = __builtin_amdgcn_mfma_f32_16x16x32_bf16(vf[md][kk], u.v, accO[md][ni], 0, 0, 0);
        }
    }
#pragma unroll
    for (int ni = 0; ni < 4; ++ni) {
        int i = ni * 16 + lr;
        if (i < 49) {
#pragma unroll
            for (int md = 0; md < 2; ++md) {
                *(uint2*)(ob + ((long)(w * 49 + i)) * 128 + h * 32 + md * 16 + g * 4) =
                    make_uint2(pkbf(accO[md][ni][0], accO[md][ni][1]),
                               pkbf(accO[md][ni][2], accO[md][ni][3]));
            }
        }
    }
}

// Fused MLP v5 = v4 schedule + sigmoid-gelu + packed bf16 cvt (VALU diet).
__global__ __launch_bounds__(256, 3) void mlp_fused(
    const unsigned short* __restrict__ A,     // h2n [M][128] bf16
    const unsigned short* __restrict__ W1,    // [512][128] bf16
    const unsigned short* __restrict__ W2,    // [128][512] bf16
    const float* __restrict__ b1,             // [512]
    const float* __restrict__ b2,             // [128]
    const unsigned short* __restrict__ resid, // x2b [M][128] bf16
    float* __restrict__ out)                  // [M][128] fp32
{
    __shared__ char ldsW[32768];
    __shared__ char ldsP[16384];
    const int tid = threadIdx.x;
    const int wid = tid >> 6, lane = tid & 63;
    const int g = lane >> 4, lr = lane & 15;
    const int wm = wid >> 1, wn = wid & 1;
    const int mbase = blockIdx.x * 64;

    bf16x8 af[2][4];
#pragma unroll
    for (int mi = 0; mi < 2; ++mi) {
        const long rb = (long)(mbase + wm * 32 + mi * 16 + lr) * 128;
#pragma unroll
        for (int kk = 0; kk < 4; ++kk)
            af[mi][kk] = *(const bf16x8*)(A + rb + kk * 32 + g * 8);
    }

    auto stageW1 = [&](int c) {
#pragma unroll
        for (int i = 0; i < 8; ++i) {
            const int cb = i * 4 + wid;
            const int r  = cb * 4 + g;
            const int s  = lr ^ (r & 15);
            async_copy16(ldsW + cb * 1024, (const char*)W1 + (long)(c * 128 + r) * 256 + s * 16);
        }
    };

    stageW1(0);
    f32x4 oacc[2][4] = {};

    for (int c = 0; c < 4; ++c) {
        __syncthreads();
#pragma unroll
        for (int hh = 0; hh < 2; ++hh) {
            f32x4 pacc[2][2] = {};
#pragma unroll
            for (int kk = 0; kk < 4; ++kk) {
                bf16x8 w1f[2];
#pragma unroll
                for (int ni = 0; ni < 2; ++ni) {
                    const int rb = hh * 64 + wn * 32 + ni * 16 + lr;
                    w1f[ni] = *(const bf16x8*)(ldsW + rb * 256 + (((kk * 4 + g) ^ (rb & 15)) * 16));
                }
#pragma unroll
                for (int mi = 0; mi < 2; ++mi)
#pragma unroll
                    for (int ni = 0; ni < 2; ++ni)
                        pacc[mi][ni] = __builtin_amdgcn_mfma_f32_16x16x32_bf16(w1f[ni], af[mi][kk], pacc[mi][ni], 0, 0, 0);
            }
#pragma unroll
            for (int mi = 0; mi < 2; ++mi) {
                const int m = wm * 32 + mi * 16 + lr;
#pragma unroll
                for (int ni = 0; ni < 2; ++ni) {
                    const int h0 = hh * 64 + wn * 32 + ni * 16 + g * 4;
                    const f32x4 b4 = *(const f32x4*)&b1[c * 128 + h0];
                    *(uint2*)(ldsP + m * 256 + (((h0 >> 3) ^ (m & 15)) * 16) + (g & 1) * 8) =
                        make_uint2(pkbf(gelu_s(pacc[mi][ni][0] + b4[0]), gelu_s(pacc[mi][ni][1] + b4[1])),
                                   pkbf(gelu_s(pacc[mi][ni][2] + b4[2]), gelu_s(pacc[mi][ni][3] + b4[3])));
                }
            }
        }
        __syncthreads();
        if (c < 3) stageW1(c + 1);
#pragma unroll
        for (int kk = 0; kk < 4; ++kk) {
            bf16x8 pf[2], w2f[4];
#pragma unroll
            for (int mi = 0; mi < 2; ++mi) {
                const int ra = wm * 32 + mi * 16 + lr;
                pf[mi] = *(const bf16x8*)(ldsP + ra * 256 + (((kk * 4 + g) ^ (ra & 15)) * 16));
            }
#pragma unroll
            for (int ni = 0; ni < 4; ++ni)
                w2f[ni] = *(const bf16x8*)(W2 + (long)(wn * 64 + ni * 16 + lr) * 512 + c * 128 + kk * 32 + g * 8);
#pragma unroll
            for (int mi = 0; mi < 2; ++mi)
#pragma unroll
                for (int ni = 0; ni < 4; ++ni)
                    oacc[mi][ni] = __builtin_amdgcn_mfma_f32_16x16x32_bf16(w2f[ni], pf[mi], oacc[mi][ni], 0, 0, 0);
        }
    }

#pragma unroll
    for (int mi = 0; mi < 2; ++mi) {
        const long gm = mbase + wm * 32 + mi * 16 + lr;
#pragma unroll
        for (int ni = 0; ni < 4; ++ni) {
            const int n0 = wn * 64 + ni * 16 + g * 4;
            const f32x4 b4 = *(const f32x4*)&b2[n0];
            const ushort4 r4 = *(const ushort4*)(resid + gm * C + n0);
            f32x4 o4;
            o4[0] = oacc[mi][ni][0] + b4[0] + bf2f(r4.x);
            o4[1] = oacc[mi][ni][1] + b4[1] + bf2f(r4.y);
            o4[2] = oacc[mi][ni][2] + b4[2] + bf2f(r4.z);
            o4[3] = oacc[mi][ni][3] + b4[3] + bf2f(r4.w);
            *(f32x4*)(out + gm * C + n0) = o4;
        }
    }
}

extern "C" void kernel_launch(void* const* d_in, const int* in_sizes, int n_in,
                              void* d_out, int out_size, void* d_ws, size_t ws_size,
                              hipStream_t stream) {
    const float* x      = (const float*)d_in[0];
    const float* n1g    = (const float*)d_in[1];
    const float* n1b    = (const float*)d_in[2];
    const float* qkv_w  = (const float*)d_in[3];
    const float* qkv_b  = (const float*)d_in[4];
    const float* proj_w = (const float*)d_in[5];
    const float* proj_b = (const float*)d_in[6];
    const float* rpb    = (const float*)d_in[7];
    const float* n2g    = (const float*)d_in[8];
    const float* n2b    = (const float*)d_in[9];
    const float* fc1_w  = (const float*)d_in[10];
    const float* fc1_b  = (const float*)d_in[11];
    const float* fc2_w  = (const float*)d_in[12];
    const float* fc2_b  = (const float*)d_in[13];
    float* out = (float*)d_out;

    // Workspace (~206 MB):
    //  [0,SZ)       hnorm bf16
    //  [SZ,2SZ)     o bf16 (window-order rows)
    //  [2SZ,3SZ)    x2b bf16
    //  [3SZ,4SZ)    h2n bf16
    //  [4SZ,..)     weights bf16 (384KB) + biasd (64KB)
    char* ws = (char*)d_ws;
    const size_t SZ = (size_t)M * C * 2;                    // 51,380,224
    unsigned short* hnorm = (unsigned short*)(ws);
    unsigned short* o     = (unsigned short*)(ws + SZ);
    unsigned short* x2b   = (unsigned short*)(ws + 2 * SZ);
    unsigned short* h2n   = (unsigned short*)(ws + 3 * SZ);
    unsigned short* wb    = (unsigned short*)(ws + 4 * SZ);
    float* biasd          = (float*)(ws + 4 * SZ + 393216);
    unsigned short* wqkv = wb, *wproj = wb + 49152, *wfc1 = wb + 65536, *wfc2 = wb + 131072;

    wconv_kernel<<<768, 256, 0, stream>>>(qkv_w, proj_w, fc1_w, fc2_w, rpb, biasd, wb);
    ln_kernel<<<M / 4, 256, 0, stream>>>(x, n1g, n1b, hnorm);
    qkv_attn<<<NWIN, 256, 0, stream>>>(hnorm, wqkv, qkv_b, biasd, o);
    gemm_pipe<1, 128, 1, false><<<M / 128, 256, 0, stream>>>(o, wproj, proj_b, x, nullptr, n2g, n2b, nullptr, h2n, x2b);
    mlp_fused<<<M / 64, 256, 0, stream>>>(h2n, wfc1, wfc2, fc1_b, fc2_b, x2b, out);
}